// Round 10
// baseline (6325.985 us; speedup 1.0000x reference)
//
#include <hip/hip_runtime.h>
#include <hip/hip_bf16.h>
#include <cstdint>
#include <cstddef>

#define NN 20000
#define HH 128
#define MM 16
#define KK 4000
#define EE 400000

typedef __attribute__((ext_vector_type(16))) float f16v;   // register vector
typedef __attribute__((ext_vector_type(4))) float f4v;     // register vector
typedef __attribute__((ext_vector_type(4), may_alias)) float f4ma;
typedef __attribute__((ext_vector_type(2), may_alias)) float f2ma;
typedef unsigned __attribute__((may_alias)) u32ma;

__device__ __forceinline__ float gelu_f(float x) {
  return 0.5f * x * (1.0f + erff(x * 0.70710678118654752440f));
}

__device__ __forceinline__ unsigned short f2bf(float f) {
  union { float f; unsigned u; } v; v.f = f;
  unsigned u = v.u;
  unsigned r = (u + 0x7FFFu + ((u >> 16) & 1u)) >> 16;  // RNE
  return (unsigned short)r;
}
__device__ __forceinline__ float bf2f(unsigned short s) {
  union { unsigned u; float f; } v; v.u = ((unsigned)s) << 16; return v.f;
}
__device__ __forceinline__ void unpack2(unsigned w, float& lo, float& hi) {
  lo = bf2f((unsigned short)(w & 0xFFFFu));
  hi = bf2f((unsigned short)(w >> 16));
}

// ---------------- GCN helper kernels (validated) ----------------

__global__ void zero2_kernel(int* __restrict__ a, int* __restrict__ b, int n) {
  int i = blockIdx.x * 256 + threadIdx.x;
  if (i < n) { a[i] = 0; b[i] = 0; }
}

__global__ void count_kernel(const int* __restrict__ dst, int* __restrict__ cnt, int n) {
  int e = blockIdx.x * 256 + threadIdx.x;
  if (e < n) atomicAdd(&cnt[dst[e]], 1);
}

__global__ void dinv_kernel(const int* __restrict__ cnt, float* __restrict__ dinv, int n) {
  int i = blockIdx.x * 256 + threadIdx.x;
  if (i < n) dinv[i] = rsqrtf((float)(cnt[i] + 1));
}

__global__ void scan_kernel(const int* __restrict__ cnt, int* __restrict__ offs, int n) {
  __shared__ int sh[1024];
  __shared__ int carry_s;
  int tid = threadIdx.x;
  if (tid == 0) carry_s = 0;
  __syncthreads();
  for (int base = 0; base < n; base += 1024) {
    int i = base + tid;
    int v = (i < n) ? cnt[i] : 0;
    sh[tid] = v;
    __syncthreads();
    for (int off = 1; off < 1024; off <<= 1) {
      int t = (tid >= off) ? sh[tid - off] : 0;
      __syncthreads();
      sh[tid] += t;
      __syncthreads();
    }
    int carry = carry_s;
    if (i < n) offs[i] = carry + sh[tid] - v;
    __syncthreads();
    if (tid == 1023) carry_s = carry + sh[1023];
    __syncthreads();
  }
  if (tid == 0) offs[n] = carry_s;
}

__global__ void fillcsr_kernel(const int* __restrict__ esrc, const int* __restrict__ edst,
                               const int* __restrict__ offs, int* __restrict__ cursor,
                               const float* __restrict__ dinv,
                               int* __restrict__ csrc, float* __restrict__ cnorm, int n) {
  int e = blockIdx.x * 256 + threadIdx.x;
  if (e < n) {
    int s = esrc[e], d = edst[e];
    int pos = offs[d] + atomicAdd(&cursor[d], 1);
    csrc[pos] = s;
    cnorm[pos] = dinv[s] * dinv[d];
  }
}

__global__ __launch_bounds__(128) void agg_kernel(const float* __restrict__ X,
    const int* __restrict__ csrc, const float* __restrict__ cnorm,
    const int* __restrict__ offs, const float* __restrict__ dinv,
    const float* __restrict__ bias, int relu, float* __restrict__ Y) {
  int i = blockIdx.x, c = threadIdx.x;
  float di = dinv[i];
  float acc = X[(size_t)i * HH + c] * di * di;
  int s = offs[i], e = offs[i + 1];
  for (int j = s; j < e; ++j) {
    acc += X[(size_t)csrc[j] * HH + c] * cnorm[j];
  }
  acc += bias[c];
  if (relu) acc = fmaxf(acc, 0.f);
  Y[(size_t)i * HH + c] = acc;
}

__global__ __launch_bounds__(128) void gemm128_kernel(const float* __restrict__ X,
    const float* __restrict__ W, float* __restrict__ Y, int nrows) {
  __shared__ float Ws[128 * 129];
  __shared__ float Xs[8 * 128];
  int tid = threadIdx.x;
  for (int idx = tid; idx < 16384; idx += 128) {
    int o = idx >> 7, k = idx & 127;
    Ws[o * 129 + k] = W[idx];
  }
  __syncthreads();
  for (int row0 = blockIdx.x * 8; row0 < nrows; row0 += gridDim.x * 8) {
    int nr = min(8, nrows - row0);
    for (int idx = tid; idx < nr * 128; idx += 128) Xs[idx] = X[(size_t)row0 * 128 + idx];
    __syncthreads();
    float acc[8] = {0, 0, 0, 0, 0, 0, 0, 0};
    for (int k = 0; k < 128; ++k) {
      float w = Ws[tid * 129 + k];
#pragma unroll
      for (int r = 0; r < 8; ++r) acc[r] += w * Xs[r * 128 + k];
    }
    for (int r = 0; r < nr; ++r) Y[(size_t)(row0 + r) * 128 + tid] = acc[r];
    __syncthreads();
  }
}

__global__ void mask_kernel(const int* __restrict__ nodes, float* __restrict__ H, int kn) {
  int idx = blockIdx.x * 256 + threadIdx.x;
  if (idx < kn * HH) {
    int j = idx >> 7, c = idx & 127;
    H[(size_t)nodes[j] * HH + c] = 0.f;
  }
}

__global__ void bcast_kernel(float* __restrict__ out, int total) {
  int idx = blockIdx.x * 256 + threadIdx.x + 128;
  if (idx < total) out[idx] = out[idx & 127];
}

// ---------------- mixer v10: v9 math, round-1 sync (no inline-asm fences) ----------------
// Every wave runs EXACTLY niter iterations (inactive items masked), so plain
// __syncthreads() is the phase fence. All LDS accesses are direct shared-array
// indexing. No asm, no sched_barrier in the loop — the round-1 clean-traffic idiom.

__global__ __launch_bounds__(512) void mixer10_kernel(
    const float* __restrict__ hbufs,  // [7][NN][HH]
    const float* __restrict__ tn_g, const float* __restrict__ tn_b,
    const float* __restrict__ tok_w1, const float* __restrict__ tok_b1,
    const float* __restrict__ tok_w2, const float* __restrict__ tok_b2,
    const float* __restrict__ cn_g, const float* __restrict__ cn_b,
    const float* __restrict__ ch_w1, const float* __restrict__ ch_b1,
    const float* __restrict__ ch_w2, const float* __restrict__ ch_b2,
    float* __restrict__ out, int total_items, int niter) {
  __shared__ __align__(16) unsigned short Wt1[128 * 128];  // 32 KB, [k][o] bf16
  __shared__ __align__(16) unsigned short Wt2[128 * 128];  // 32 KB
  __shared__ __align__(16) float zf[8][16 * 132];          // 67.6 KB per-wave tiles
  __shared__ float tg[128], tbv[128], cg[128], cbv[128], cb1v[128], cb2v[128];
  __shared__ float tw1s[256], tw2s[256], tb1s[16], tb2s[16];

  const int tid = threadIdx.x;

  for (int idx = tid; idx < 16384; idx += 512) {
    int o = idx >> 7, k = idx & 127;
    Wt1[k * 128 + o] = f2bf(ch_w1[idx]);
    Wt2[k * 128 + o] = f2bf(ch_w2[idx]);
  }
  if (tid < 128) {
    tg[tid] = tn_g[tid]; tbv[tid] = tn_b[tid];
    cg[tid] = cn_g[tid]; cbv[tid] = cn_b[tid];
    cb1v[tid] = ch_b1[tid]; cb2v[tid] = ch_b2[tid];
  }
  if (tid < 256) { tw1s[tid] = tok_w1[tid]; tw2s[tid] = tok_w2[tid]; }
  if (tid < 16) { tb1s[tid] = tok_b1[tid]; tb2s[tid] = tok_b2[tid]; }
  __syncthreads();

  const int wid = tid >> 6;
  const int lane = tid & 63;
  const int q = lane >> 4;
  const int h = lane & 15;
  const int cb = q * 32 + 2 * h;

  const int gwave = blockIdx.x * 8 + wid;
  const int wstride = gridDim.x * 8;

  for (int it = 0; it < niter; ++it) {
    const int item = gwave + it * wstride;
    const bool active = item < total_items;
    int t = 0, node = 0;
    if (active && item < 7 * NN) { t = item / NN + 1; node = item % NN; }

    // ---- P1+P2: load row h, LN1 stats, write RAW x + (mu,rs) to tile ----
    {
      f16v xlo, xhi;
      int src_t = h - (MM - t);
      if (active && src_t >= 0) {
        const float* hp = hbufs + ((size_t)src_t * NN + node) * HH + q * 32;
#pragma unroll
        for (int j = 0; j < 4; ++j) {
          f4ma v = *(const f4ma*)(hp + 4 * j);
          xlo[4 * j] = v.x; xlo[4 * j + 1] = v.y; xlo[4 * j + 2] = v.z; xlo[4 * j + 3] = v.w;
        }
#pragma unroll
        for (int j = 0; j < 4; ++j) {
          f4ma v = *(const f4ma*)(hp + 16 + 4 * j);
          xhi[4 * j] = v.x; xhi[4 * j + 1] = v.y; xhi[4 * j + 2] = v.z; xhi[4 * j + 3] = v.w;
        }
      } else {
#pragma unroll
        for (int j = 0; j < 16; ++j) { xlo[j] = 0.f; xhi[j] = 0.f; }
      }
      float s = 0.f, ss = 0.f;
#pragma unroll
      for (int j = 0; j < 16; ++j) {
        s += xlo[j] + xhi[j];
        ss += xlo[j] * xlo[j] + xhi[j] * xhi[j];
      }
      s += __shfl_xor(s, 16); ss += __shfl_xor(ss, 16);
      s += __shfl_xor(s, 32); ss += __shfl_xor(ss, 32);
      float mu = s * (1.f / 128.f);
      float var = fmaxf(ss * (1.f / 128.f) - mu * mu, 0.f);
      float rs = rsqrtf(var + 1e-5f);
#pragma unroll
      for (int m = 0; m < 4; ++m) {
        f2ma* dst = (f2ma*)&zf[wid][h * 132 + q * 32 + 4 * m];
        f4ma w;
        w.x = xlo[4 * m]; w.y = xlo[4 * m + 1]; w.z = xlo[4 * m + 2]; w.w = xlo[4 * m + 3];
        *(f4ma*)dst = w;
      }
#pragma unroll
      for (int m = 0; m < 4; ++m) {
        f4ma w;
        w.x = xhi[4 * m]; w.y = xhi[4 * m + 1]; w.z = xhi[4 * m + 2]; w.w = xhi[4 * m + 3];
        *(f4ma*)&zf[wid][h * 132 + q * 32 + 16 + 4 * m] = w;
      }
      if (q == 0) {
        zf[wid][h * 132 + 128] = mu;
        zf[wid][h * 132 + 129] = rs;
      }
    }
    __syncthreads();   // (1) x + (mu,rs) visible

    // ---- P3: column pass — LN1 on the fly, token-MLP, residual, colsum ----
    float cs0, cs1;
    {
      f16v xv0, xv1, a0v, a1v;
      const float tg0 = tg[cb], tb0 = tbv[cb], tg1 = tg[cb + 1], tb1 = tbv[cb + 1];
#pragma unroll
      for (int hd = 0; hd < 16; ++hd) { float b = tb1s[hd]; a0v[hd] = b; a1v[hd] = b; }
#pragma unroll
      for (int r = 0; r < 16; ++r) {
        f2ma v = *(const f2ma*)&zf[wid][r * 132 + cb];
        float mu = zf[wid][r * 132 + 128];   // uniform addr -> broadcast
        float rs = zf[wid][r * 132 + 129];
        xv0[r] = v.x; xv1[r] = v.y;
        float z0 = (v.x - mu) * rs * tg0 + tb0;
        float z1 = (v.y - mu) * rs * tg1 + tb1;
#pragma unroll
        for (int hd = 0; hd < 16; ++hd) {
          float w = tw1s[hd * 16 + r];
          a0v[hd] += w * z0; a1v[hd] += w * z1;
        }
      }
#pragma unroll
      for (int hd = 0; hd < 16; ++hd) { a0v[hd] = gelu_f(a0v[hd]); a1v[hd] = gelu_f(a1v[hd]); }
      cs0 = 0.f; cs1 = 0.f;
#pragma unroll
      for (int r = 0; r < 16; ++r) {
        float o0 = tb2s[r], o1 = tb2s[r];
#pragma unroll
        for (int hd = 0; hd < 16; ++hd) {
          float w = tw2s[r * 16 + hd];
          o0 += w * a0v[hd]; o1 += w * a1v[hd];
        }
        float nx0 = xv0[r] + o0, nx1 = xv1[r] + o1;   // x_new
        cs0 += nx0; cs1 += nx1;                        // lane-local token-sum
        f2ma v; v.x = nx0; v.y = nx1;
        *(f2ma*)&zf[wid][r * 132 + cb] = v;
      }
    }
    __syncthreads();   // (2) x_new visible

    // ---- P4: row pass — LN2 -> z2 (cell-private per lane) ----
    {
      f16v xlo, xhi;
#pragma unroll
      for (int j = 0; j < 4; ++j) {
        f4ma v = *(const f4ma*)&zf[wid][h * 132 + q * 32 + 4 * j];
        xlo[4 * j] = v.x; xlo[4 * j + 1] = v.y; xlo[4 * j + 2] = v.z; xlo[4 * j + 3] = v.w;
      }
#pragma unroll
      for (int j = 0; j < 4; ++j) {
        f4ma v = *(const f4ma*)&zf[wid][h * 132 + q * 32 + 16 + 4 * j];
        xhi[4 * j] = v.x; xhi[4 * j + 1] = v.y; xhi[4 * j + 2] = v.z; xhi[4 * j + 3] = v.w;
      }
      float s = 0.f, ss = 0.f;
#pragma unroll
      for (int j = 0; j < 16; ++j) {
        s += xlo[j] + xhi[j];
        ss += xlo[j] * xlo[j] + xhi[j] * xhi[j];
      }
      s += __shfl_xor(s, 16); ss += __shfl_xor(ss, 16);
      s += __shfl_xor(s, 32); ss += __shfl_xor(ss, 32);
      float mu = s * (1.f / 128.f);
      float var = fmaxf(ss * (1.f / 128.f) - mu * mu, 0.f);
      float rs = rsqrtf(var + 1e-5f);
#pragma unroll
      for (int m = 0; m < 4; ++m) {
        f4ma w;
        int c = q * 32 + 4 * m;
        w.x = (xlo[4 * m]     - mu) * rs * cg[c]     + cbv[c];
        w.y = (xlo[4 * m + 1] - mu) * rs * cg[c + 1] + cbv[c + 1];
        w.z = (xlo[4 * m + 2] - mu) * rs * cg[c + 2] + cbv[c + 2];
        w.w = (xlo[4 * m + 3] - mu) * rs * cg[c + 3] + cbv[c + 3];
        *(f4ma*)&zf[wid][h * 132 + c] = w;
      }
#pragma unroll
      for (int m = 0; m < 4; ++m) {
        f4ma w;
        int c = q * 32 + 16 + 4 * m;
        w.x = (xhi[4 * m]     - mu) * rs * cg[c]     + cbv[c];
        w.y = (xhi[4 * m + 1] - mu) * rs * cg[c + 1] + cbv[c + 1];
        w.z = (xhi[4 * m + 2] - mu) * rs * cg[c + 2] + cbv[c + 2];
        w.w = (xhi[4 * m + 3] - mu) * rs * cg[c + 3] + cbv[c + 3];
        *(f4ma*)&zf[wid][h * 132 + c] = w;
      }
    }
    __syncthreads();   // (3) z2 visible

    // ---- P5: channel matmul1 (f32 VALU): hidden = gelu(z2 @ W1^T + b1) ----
    f16v h0v, h1v;
    {
      float b0 = cb1v[cb], b1 = cb1v[cb + 1];
#pragma unroll
      for (int r = 0; r < 16; ++r) { h0v[r] = b0; h1v[r] = b1; }
      for (int k = 0; k < 128; k += 4) {
        f4v w0v, w1v;
#pragma unroll
        for (int kk = 0; kk < 4; ++kk) {
          unsigned w = *(const u32ma*)&Wt1[(k + kk) * 128 + cb];
          float lo, hi; unpack2(w, lo, hi);
          w0v[kk] = lo; w1v[kk] = hi;
        }
#pragma unroll
        for (int r = 0; r < 16; ++r) {
          f4ma z4 = *(const f4ma*)&zf[wid][r * 132 + k];   // uniform addr -> broadcast
          h0v[r] += z4.x * w0v[0] + z4.y * w0v[1] + z4.z * w0v[2] + z4.w * w0v[3];
          h1v[r] += z4.x * w1v[0] + z4.y * w1v[1] + z4.z * w1v[2] + z4.w * w1v[3];
        }
      }
#pragma unroll
      for (int r = 0; r < 16; ++r) { h0v[r] = gelu_f(h0v[r]); h1v[r] = gelu_f(h1v[r]); }
    }
    __syncthreads();   // (4) all z2 reads complete before overwrite

#pragma unroll
    for (int r = 0; r < 16; ++r) {
      f2ma v; v.x = h0v[r]; v.y = h1v[r];
      *(f2ma*)&zf[wid][r * 132 + cb] = v;
    }
    __syncthreads();   // (5) hidden visible

    // ---- P6: channel matmul2 (f32 VALU) + lane-local colsum ----
    float cc0, cc1;
    {
      f16v acc0, acc1;
      float b0 = cb2v[cb], b1 = cb2v[cb + 1];
#pragma unroll
      for (int r = 0; r < 16; ++r) { acc0[r] = b0; acc1[r] = b1; }
      for (int k = 0; k < 128; k += 4) {
        f4v w0v, w1v;
#pragma unroll
        for (int kk = 0; kk < 4; ++kk) {
          unsigned w = *(const u32ma*)&Wt2[(k + kk) * 128 + cb];
          float lo, hi; unpack2(w, lo, hi);
          w0v[kk] = lo; w1v[kk] = hi;
        }
#pragma unroll
        for (int r = 0; r < 16; ++r) {
          f4ma z4 = *(const f4ma*)&zf[wid][r * 132 + k];
          acc0[r] += z4.x * w0v[0] + z4.y * w0v[1] + z4.z * w0v[2] + z4.w * w0v[3];
          acc1[r] += z4.x * w1v[0] + z4.y * w1v[1] + z4.z * w1v[2] + z4.w * w1v[3];
        }
      }
      cc0 = 0.f; cc1 = 0.f;
#pragma unroll
      for (int r = 0; r < 16; ++r) { cc0 += acc0[r]; cc1 += acc1[r]; }
    }

    // ---- P7: write output (all lane-local) ----
    if (active) {
      f2ma o;
      o.x = (cs0 + cc0) * (1.f / 16.f);
      o.y = (cs1 + cc1) * (1.f / 16.f);
      *(f2ma*)&out[((size_t)t * NN + node) * HH + cb] = o;
    }
    __syncthreads();   // (6) tile reuse next iteration
  }
}

// ---------------- launch ----------------

extern "C" void kernel_launch(void* const* d_in, const int* in_sizes, int n_in,
                              void* d_out, int out_size, void* d_ws, size_t ws_size,
                              hipStream_t stream) {
  const int* node_t   = (const int*)d_in[0];
  const int* edges    = (const int*)d_in[1];
  const float* emb    = (const float*)d_in[3];
  const float* convW1 = (const float*)d_in[4];
  const float* convb1 = (const float*)d_in[5];
  const float* convW2 = (const float*)d_in[6];
  const float* convb2 = (const float*)d_in[7];
  const float* tn_g   = (const float*)d_in[8];
  const float* tn_b   = (const float*)d_in[9];
  const float* tok_w1 = (const float*)d_in[10];
  const float* tok_b1 = (const float*)d_in[11];
  const float* tok_w2 = (const float*)d_in[12];
  const float* tok_b2 = (const float*)d_in[13];
  const float* cn_g   = (const float*)d_in[14];
  const float* cn_b   = (const float*)d_in[15];
  const float* ch_w1  = (const float*)d_in[16];
  const float* ch_b1  = (const float*)d_in[17];
  const float* ch_w2  = (const float*)d_in[18];
  const float* ch_b2  = (const float*)d_in[19];
  float* out = (float*)d_out;

  char* ws = (char*)d_ws;
  size_t off = 0;
  auto alloc = [&](size_t bytes) -> void* {
    void* p = ws + off;
    off += (bytes + 511) & ~(size_t)511;
    return p;
  };
  float* xw1   = (float*)alloc((size_t)NN * HH * 4);
  float* hbufs = (float*)alloc((size_t)7 * NN * HH * 4);
  float* h     = (float*)alloc((size_t)NN * HH * 4);
  float* h2    = (float*)alloc((size_t)NN * HH * 4);
  float* dinv  = (float*)alloc((size_t)NN * 4);
  int*   cnt   = (int*)alloc((size_t)NN * 4);
  int*   cursor= (int*)alloc((size_t)NN * 4);
  int*   offs  = (int*)alloc((size_t)(NN + 1) * 4);
  int*   csrc  = (int*)alloc((size_t)EE * 4);
  float* cnorm = (float*)alloc((size_t)EE * 4);

  gemm128_kernel<<<512, 128, 0, stream>>>(emb, convW1, xw1, NN);

  for (int t = 0; t < 7; ++t) {
    const int* es = edges + (size_t)t * 2 * EE;
    const int* ed = es + EE;
    zero2_kernel<<<(NN + 255) / 256, 256, 0, stream>>>(cnt, cursor, NN);
    count_kernel<<<(EE + 255) / 256, 256, 0, stream>>>(ed, cnt, EE);
    dinv_kernel<<<(NN + 255) / 256, 256, 0, stream>>>(cnt, dinv, NN);
    scan_kernel<<<1, 1024, 0, stream>>>(cnt, offs, NN);
    fillcsr_kernel<<<(EE + 255) / 256, 256, 0, stream>>>(es, ed, offs, cursor, dinv,
                                                         csrc, cnorm, EE);
    agg_kernel<<<NN, 128, 0, stream>>>(xw1, csrc, cnorm, offs, dinv, convb1, 1, h);
    gemm128_kernel<<<512, 128, 0, stream>>>(h, convW2, h2, NN);
    agg_kernel<<<NN, 128, 0, stream>>>(h2, csrc, cnorm, offs, dinv, convb2, 0,
                                       hbufs + (size_t)t * NN * HH);
    mask_kernel<<<(KK * HH + 255) / 256, 256, 0, stream>>>(
        node_t + (size_t)t * KK, hbufs + (size_t)t * NN * HH, KK);
  }

  // One fused launch: items [0, 7*NN) = (t=1..7, node); item 7*NN = (t=0, node 0)
  const int total_items = 7 * NN + 1;
  const int nwaves = 256 * 8;
  const int niter = (total_items + nwaves - 1) / nwaves;
  mixer10_kernel<<<256, 512, 0, stream>>>(hbufs, tn_g, tn_b, tok_w1, tok_b1, tok_w2,
                                          tok_b2, cn_g, cn_b, ch_w1, ch_b1, ch_w2, ch_b2,
                                          out, total_items, niter);
  bcast_kernel<<<((NN * HH - 128) + 255) / 256, 256, 0, stream>>>(out, NN * HH);
}

// Round 11
// 6078.020 us; speedup vs baseline: 1.0408x; 1.0408x over previous
//
#include <hip/hip_runtime.h>
#include <hip/hip_bf16.h>
#include <cstdint>
#include <cstddef>

#define NN 20000
#define HH 128
#define MM 16
#define KK 4000
#define EE 400000

typedef __attribute__((ext_vector_type(16))) float f16v;   // register vector
typedef __attribute__((ext_vector_type(4))) float f4v;     // register vector
typedef __attribute__((ext_vector_type(4), may_alias)) float f4ma;
typedef __attribute__((ext_vector_type(2), may_alias)) float f2ma;
typedef unsigned __attribute__((may_alias)) u32ma;

__device__ __forceinline__ float gelu_f(float x) {
  return 0.5f * x * (1.0f + erff(x * 0.70710678118654752440f));
}

__device__ __forceinline__ unsigned short f2bf(float f) {
  union { float f; unsigned u; } v; v.f = f;
  unsigned u = v.u;
  unsigned r = (u + 0x7FFFu + ((u >> 16) & 1u)) >> 16;  // RNE
  return (unsigned short)r;
}
__device__ __forceinline__ float bf2f(unsigned short s) {
  union { unsigned u; float f; } v; v.u = ((unsigned)s) << 16; return v.f;
}
__device__ __forceinline__ void unpack2(unsigned w, float& lo, float& hi) {
  lo = bf2f((unsigned short)(w & 0xFFFFu));
  hi = bf2f((unsigned short)(w >> 16));
}

// ---------------- GCN helper kernels (validated) ----------------

__global__ void zero2_kernel(int* __restrict__ a, int* __restrict__ b, int n) {
  int i = blockIdx.x * 256 + threadIdx.x;
  if (i < n) { a[i] = 0; b[i] = 0; }
}

__global__ void count_kernel(const int* __restrict__ dst, int* __restrict__ cnt, int n) {
  int e = blockIdx.x * 256 + threadIdx.x;
  if (e < n) atomicAdd(&cnt[dst[e]], 1);
}

__global__ void dinv_kernel(const int* __restrict__ cnt, float* __restrict__ dinv, int n) {
  int i = blockIdx.x * 256 + threadIdx.x;
  if (i < n) dinv[i] = rsqrtf((float)(cnt[i] + 1));
}

__global__ void scan_kernel(const int* __restrict__ cnt, int* __restrict__ offs, int n) {
  __shared__ int sh[1024];
  __shared__ int carry_s;
  int tid = threadIdx.x;
  if (tid == 0) carry_s = 0;
  __syncthreads();
  for (int base = 0; base < n; base += 1024) {
    int i = base + tid;
    int v = (i < n) ? cnt[i] : 0;
    sh[tid] = v;
    __syncthreads();
    for (int off = 1; off < 1024; off <<= 1) {
      int t = (tid >= off) ? sh[tid - off] : 0;
      __syncthreads();
      sh[tid] += t;
      __syncthreads();
    }
    int carry = carry_s;
    if (i < n) offs[i] = carry + sh[tid] - v;
    __syncthreads();
    if (tid == 1023) carry_s = carry + sh[1023];
    __syncthreads();
  }
  if (tid == 0) offs[n] = carry_s;
}

__global__ void fillcsr_kernel(const int* __restrict__ esrc, const int* __restrict__ edst,
                               const int* __restrict__ offs, int* __restrict__ cursor,
                               const float* __restrict__ dinv,
                               int* __restrict__ csrc, float* __restrict__ cnorm, int n) {
  int e = blockIdx.x * 256 + threadIdx.x;
  if (e < n) {
    int s = esrc[e], d = edst[e];
    int pos = offs[d] + atomicAdd(&cursor[d], 1);
    csrc[pos] = s;
    cnorm[pos] = dinv[s] * dinv[d];
  }
}

__global__ __launch_bounds__(128) void agg_kernel(const float* __restrict__ X,
    const int* __restrict__ csrc, const float* __restrict__ cnorm,
    const int* __restrict__ offs, const float* __restrict__ dinv,
    const float* __restrict__ bias, int relu, float* __restrict__ Y) {
  int i = blockIdx.x, c = threadIdx.x;
  float di = dinv[i];
  float acc = X[(size_t)i * HH + c] * di * di;
  int s = offs[i], e = offs[i + 1];
  for (int j = s; j < e; ++j) {
    acc += X[(size_t)csrc[j] * HH + c] * cnorm[j];
  }
  acc += bias[c];
  if (relu) acc = fmaxf(acc, 0.f);
  Y[(size_t)i * HH + c] = acc;
}

__global__ __launch_bounds__(128) void gemm128_kernel(const float* __restrict__ X,
    const float* __restrict__ W, float* __restrict__ Y, int nrows) {
  __shared__ float Ws[128 * 129];
  __shared__ float Xs[8 * 128];
  int tid = threadIdx.x;
  for (int idx = tid; idx < 16384; idx += 128) {
    int o = idx >> 7, k = idx & 127;
    Ws[o * 129 + k] = W[idx];
  }
  __syncthreads();
  for (int row0 = blockIdx.x * 8; row0 < nrows; row0 += gridDim.x * 8) {
    int nr = min(8, nrows - row0);
    for (int idx = tid; idx < nr * 128; idx += 128) Xs[idx] = X[(size_t)row0 * 128 + idx];
    __syncthreads();
    float acc[8] = {0, 0, 0, 0, 0, 0, 0, 0};
    for (int k = 0; k < 128; ++k) {
      float w = Ws[tid * 129 + k];
#pragma unroll
      for (int r = 0; r < 8; ++r) acc[r] += w * Xs[r * 128 + k];
    }
    for (int r = 0; r < nr; ++r) Y[(size_t)(row0 + r) * 128 + tid] = acc[r];
    __syncthreads();
  }
}

__global__ void mask_kernel(const int* __restrict__ nodes, float* __restrict__ H, int kn) {
  int idx = blockIdx.x * 256 + threadIdx.x;
  if (idx < kn * HH) {
    int j = idx >> 7, c = idx & 127;
    H[(size_t)nodes[j] * HH + c] = 0.f;
  }
}

__global__ void bcast_kernel(float* __restrict__ out, int total) {
  int idx = blockIdx.x * 256 + threadIdx.x + 128;
  if (idx < total) out[idx] = out[idx & 127];
}

// ---------------- mixer v11: v10 + waves_per_eu(1,2) + reduced P3 live set ----------------
// LDS (138.7 KB) forces 1 block/CU = 2 waves/EU, so tell the register allocator
// exactly that (amdgpu_waves_per_eu(1,2)) -> VGPR budget 256, no heuristic spills.
// P3 no longer caches xv0/xv1: second loop re-reads x from the lane-private LDS
// column (in-place safe), cutting 32 regs off the peak live set.

__global__ __launch_bounds__(512)
__attribute__((amdgpu_waves_per_eu(1, 2)))
void mixer11_kernel(
    const float* __restrict__ hbufs,  // [7][NN][HH]
    const float* __restrict__ tn_g, const float* __restrict__ tn_b,
    const float* __restrict__ tok_w1, const float* __restrict__ tok_b1,
    const float* __restrict__ tok_w2, const float* __restrict__ tok_b2,
    const float* __restrict__ cn_g, const float* __restrict__ cn_b,
    const float* __restrict__ ch_w1, const float* __restrict__ ch_b1,
    const float* __restrict__ ch_w2, const float* __restrict__ ch_b2,
    float* __restrict__ out, int total_items, int niter) {
  __shared__ __align__(16) unsigned short Wt1[128 * 128];  // 32 KB, [k][o] bf16
  __shared__ __align__(16) unsigned short Wt2[128 * 128];  // 32 KB
  __shared__ __align__(16) float zf[8][16 * 132];          // 67.6 KB per-wave tiles
  __shared__ float tg[128], tbv[128], cg[128], cbv[128], cb1v[128], cb2v[128];
  __shared__ float tw1s[256], tw2s[256], tb1s[16], tb2s[16];

  const int tid = threadIdx.x;

  for (int idx = tid; idx < 16384; idx += 512) {
    int o = idx >> 7, k = idx & 127;
    Wt1[k * 128 + o] = f2bf(ch_w1[idx]);
    Wt2[k * 128 + o] = f2bf(ch_w2[idx]);
  }
  if (tid < 128) {
    tg[tid] = tn_g[tid]; tbv[tid] = tn_b[tid];
    cg[tid] = cn_g[tid]; cbv[tid] = cn_b[tid];
    cb1v[tid] = ch_b1[tid]; cb2v[tid] = ch_b2[tid];
  }
  if (tid < 256) { tw1s[tid] = tok_w1[tid]; tw2s[tid] = tok_w2[tid]; }
  if (tid < 16) { tb1s[tid] = tok_b1[tid]; tb2s[tid] = tok_b2[tid]; }
  __syncthreads();

  const int wid = tid >> 6;
  const int lane = tid & 63;
  const int q = lane >> 4;
  const int h = lane & 15;
  const int cb = q * 32 + 2 * h;

  const int gwave = blockIdx.x * 8 + wid;
  const int wstride = gridDim.x * 8;

  for (int it = 0; it < niter; ++it) {
    const int item = gwave + it * wstride;
    const bool active = item < total_items;
    int t = 0, node = 0;
    if (active && item < 7 * NN) { t = item / NN + 1; node = item % NN; }

    // ---- P1+P2: load row h, LN1 stats, write RAW x + (mu,rs) to tile ----
    {
      f16v xlo, xhi;
      int src_t = h - (MM - t);
      if (active && src_t >= 0) {
        const float* hp = hbufs + ((size_t)src_t * NN + node) * HH + q * 32;
#pragma unroll
        for (int j = 0; j < 4; ++j) {
          f4ma v = *(const f4ma*)(hp + 4 * j);
          xlo[4 * j] = v.x; xlo[4 * j + 1] = v.y; xlo[4 * j + 2] = v.z; xlo[4 * j + 3] = v.w;
        }
#pragma unroll
        for (int j = 0; j < 4; ++j) {
          f4ma v = *(const f4ma*)(hp + 16 + 4 * j);
          xhi[4 * j] = v.x; xhi[4 * j + 1] = v.y; xhi[4 * j + 2] = v.z; xhi[4 * j + 3] = v.w;
        }
      } else {
#pragma unroll
        for (int j = 0; j < 16; ++j) { xlo[j] = 0.f; xhi[j] = 0.f; }
      }
      float s = 0.f, ss = 0.f;
#pragma unroll
      for (int j = 0; j < 16; ++j) {
        s += xlo[j] + xhi[j];
        ss += xlo[j] * xlo[j] + xhi[j] * xhi[j];
      }
      s += __shfl_xor(s, 16); ss += __shfl_xor(ss, 16);
      s += __shfl_xor(s, 32); ss += __shfl_xor(ss, 32);
      float mu = s * (1.f / 128.f);
      float var = fmaxf(ss * (1.f / 128.f) - mu * mu, 0.f);
      float rs = rsqrtf(var + 1e-5f);
#pragma unroll
      for (int m = 0; m < 4; ++m) {
        f4ma w;
        w.x = xlo[4 * m]; w.y = xlo[4 * m + 1]; w.z = xlo[4 * m + 2]; w.w = xlo[4 * m + 3];
        *(f4ma*)&zf[wid][h * 132 + q * 32 + 4 * m] = w;
      }
#pragma unroll
      for (int m = 0; m < 4; ++m) {
        f4ma w;
        w.x = xhi[4 * m]; w.y = xhi[4 * m + 1]; w.z = xhi[4 * m + 2]; w.w = xhi[4 * m + 3];
        *(f4ma*)&zf[wid][h * 132 + q * 32 + 16 + 4 * m] = w;
      }
      if (q == 0) {
        zf[wid][h * 132 + 128] = mu;
        zf[wid][h * 132 + 129] = rs;
      }
    }
    __syncthreads();   // (1) x + (mu,rs) visible

    // ---- P3: column pass — LN1 on the fly, token-MLP, residual, colsum ----
    float cs0, cs1;
    {
      f16v a0v, a1v;
      const float tg0 = tg[cb], tb0 = tbv[cb], tg1 = tg[cb + 1], tb1 = tbv[cb + 1];
#pragma unroll
      for (int hd = 0; hd < 16; ++hd) { float b = tb1s[hd]; a0v[hd] = b; a1v[hd] = b; }
#pragma unroll
      for (int r = 0; r < 16; ++r) {
        f2ma v = *(const f2ma*)&zf[wid][r * 132 + cb];
        float mu = zf[wid][r * 132 + 128];   // uniform addr -> broadcast
        float rs = zf[wid][r * 132 + 129];
        float z0 = (v.x - mu) * rs * tg0 + tb0;
        float z1 = (v.y - mu) * rs * tg1 + tb1;
#pragma unroll
        for (int hd = 0; hd < 16; ++hd) {
          float w = tw1s[hd * 16 + r];
          a0v[hd] += w * z0; a1v[hd] += w * z1;
        }
      }
#pragma unroll
      for (int hd = 0; hd < 16; ++hd) { a0v[hd] = gelu_f(a0v[hd]); a1v[hd] = gelu_f(a1v[hd]); }
      cs0 = 0.f; cs1 = 0.f;
#pragma unroll
      for (int r = 0; r < 16; ++r) {
        float o0 = tb2s[r], o1 = tb2s[r];
#pragma unroll
        for (int hd = 0; hd < 16; ++hd) {
          float w = tw2s[r * 16 + hd];
          o0 += w * a0v[hd]; o1 += w * a1v[hd];
        }
        f2ma v = *(const f2ma*)&zf[wid][r * 132 + cb];  // re-read x (not cached)
        float nx0 = v.x + o0, nx1 = v.y + o1;            // x_new
        cs0 += nx0; cs1 += nx1;                          // lane-local token-sum
        f2ma nv; nv.x = nx0; nv.y = nx1;
        *(f2ma*)&zf[wid][r * 132 + cb] = nv;
      }
    }
    __syncthreads();   // (2) x_new visible

    // ---- P4: row pass — LN2 -> z2 ----
    {
      f16v xlo, xhi;
#pragma unroll
      for (int j = 0; j < 4; ++j) {
        f4ma v = *(const f4ma*)&zf[wid][h * 132 + q * 32 + 4 * j];
        xlo[4 * j] = v.x; xlo[4 * j + 1] = v.y; xlo[4 * j + 2] = v.z; xlo[4 * j + 3] = v.w;
      }
#pragma unroll
      for (int j = 0; j < 4; ++j) {
        f4ma v = *(const f4ma*)&zf[wid][h * 132 + q * 32 + 16 + 4 * j];
        xhi[4 * j] = v.x; xhi[4 * j + 1] = v.y; xhi[4 * j + 2] = v.z; xhi[4 * j + 3] = v.w;
      }
      float s = 0.f, ss = 0.f;
#pragma unroll
      for (int j = 0; j < 16; ++j) {
        s += xlo[j] + xhi[j];
        ss += xlo[j] * xlo[j] + xhi[j] * xhi[j];
      }
      s += __shfl_xor(s, 16); ss += __shfl_xor(ss, 16);
      s += __shfl_xor(s, 32); ss += __shfl_xor(ss, 32);
      float mu = s * (1.f / 128.f);
      float var = fmaxf(ss * (1.f / 128.f) - mu * mu, 0.f);
      float rs = rsqrtf(var + 1e-5f);
#pragma unroll
      for (int m = 0; m < 4; ++m) {
        f4ma w;
        int c = q * 32 + 4 * m;
        w.x = (xlo[4 * m]     - mu) * rs * cg[c]     + cbv[c];
        w.y = (xlo[4 * m + 1] - mu) * rs * cg[c + 1] + cbv[c + 1];
        w.z = (xlo[4 * m + 2] - mu) * rs * cg[c + 2] + cbv[c + 2];
        w.w = (xlo[4 * m + 3] - mu) * rs * cg[c + 3] + cbv[c + 3];
        *(f4ma*)&zf[wid][h * 132 + c] = w;
      }
#pragma unroll
      for (int m = 0; m < 4; ++m) {
        f4ma w;
        int c = q * 32 + 16 + 4 * m;
        w.x = (xhi[4 * m]     - mu) * rs * cg[c]     + cbv[c];
        w.y = (xhi[4 * m + 1] - mu) * rs * cg[c + 1] + cbv[c + 1];
        w.z = (xhi[4 * m + 2] - mu) * rs * cg[c + 2] + cbv[c + 2];
        w.w = (xhi[4 * m + 3] - mu) * rs * cg[c + 3] + cbv[c + 3];
        *(f4ma*)&zf[wid][h * 132 + c] = w;
      }
    }
    __syncthreads();   // (3) z2 visible

    // ---- P5: channel matmul1 (f32 VALU): hidden = gelu(z2 @ W1^T + b1) ----
    f16v h0v, h1v;
    {
      float b0 = cb1v[cb], b1 = cb1v[cb + 1];
#pragma unroll
      for (int r = 0; r < 16; ++r) { h0v[r] = b0; h1v[r] = b1; }
      for (int k = 0; k < 128; k += 4) {
        f4v w0v, w1v;
#pragma unroll
        for (int kk = 0; kk < 4; ++kk) {
          unsigned w = *(const u32ma*)&Wt1[(k + kk) * 128 + cb];
          float lo, hi; unpack2(w, lo, hi);
          w0v[kk] = lo; w1v[kk] = hi;
        }
#pragma unroll
        for (int r = 0; r < 16; ++r) {
          f4ma z4 = *(const f4ma*)&zf[wid][r * 132 + k];   // uniform addr -> broadcast
          h0v[r] += z4.x * w0v[0] + z4.y * w0v[1] + z4.z * w0v[2] + z4.w * w0v[3];
          h1v[r] += z4.x * w1v[0] + z4.y * w1v[1] + z4.z * w1v[2] + z4.w * w1v[3];
        }
      }
#pragma unroll
      for (int r = 0; r < 16; ++r) { h0v[r] = gelu_f(h0v[r]); h1v[r] = gelu_f(h1v[r]); }
    }
    __syncthreads();   // (4) all z2 reads complete before overwrite

#pragma unroll
    for (int r = 0; r < 16; ++r) {
      f2ma v; v.x = h0v[r]; v.y = h1v[r];
      *(f2ma*)&zf[wid][r * 132 + cb] = v;
    }
    __syncthreads();   // (5) hidden visible

    // ---- P6: channel matmul2 (f32 VALU) + lane-local colsum ----
    float cc0, cc1;
    {
      f16v acc0, acc1;
      float b0 = cb2v[cb], b1 = cb2v[cb + 1];
#pragma unroll
      for (int r = 0; r < 16; ++r) { acc0[r] = b0; acc1[r] = b1; }
      for (int k = 0; k < 128; k += 4) {
        f4v w0v, w1v;
#pragma unroll
        for (int kk = 0; kk < 4; ++kk) {
          unsigned w = *(const u32ma*)&Wt2[(k + kk) * 128 + cb];
          float lo, hi; unpack2(w, lo, hi);
          w0v[kk] = lo; w1v[kk] = hi;
        }
#pragma unroll
        for (int r = 0; r < 16; ++r) {
          f4ma z4 = *(const f4ma*)&zf[wid][r * 132 + k];
          acc0[r] += z4.x * w0v[0] + z4.y * w0v[1] + z4.z * w0v[2] + z4.w * w0v[3];
          acc1[r] += z4.x * w1v[0] + z4.y * w1v[1] + z4.z * w1v[2] + z4.w * w1v[3];
        }
      }
      cc0 = 0.f; cc1 = 0.f;
#pragma unroll
      for (int r = 0; r < 16; ++r) { cc0 += acc0[r]; cc1 += acc1[r]; }
    }

    // ---- P7: write output (all lane-local) ----
    if (active) {
      f2ma o;
      o.x = (cs0 + cc0) * (1.f / 16.f);
      o.y = (cs1 + cc1) * (1.f / 16.f);
      *(f2ma*)&out[((size_t)t * NN + node) * HH + cb] = o;
    }
    __syncthreads();   // (6) tile reuse next iteration
  }
}

// ---------------- launch ----------------

extern "C" void kernel_launch(void* const* d_in, const int* in_sizes, int n_in,
                              void* d_out, int out_size, void* d_ws, size_t ws_size,
                              hipStream_t stream) {
  const int* node_t   = (const int*)d_in[0];
  const int* edges    = (const int*)d_in[1];
  const float* emb    = (const float*)d_in[3];
  const float* convW1 = (const float*)d_in[4];
  const float* convb1 = (const float*)d_in[5];
  const float* convW2 = (const float*)d_in[6];
  const float* convb2 = (const float*)d_in[7];
  const float* tn_g   = (const float*)d_in[8];
  const float* tn_b   = (const float*)d_in[9];
  const float* tok_w1 = (const float*)d_in[10];
  const float* tok_b1 = (const float*)d_in[11];
  const float* tok_w2 = (const float*)d_in[12];
  const float* tok_b2 = (const float*)d_in[13];
  const float* cn_g   = (const float*)d_in[14];
  const float* cn_b   = (const float*)d_in[15];
  const float* ch_w1  = (const float*)d_in[16];
  const float* ch_b1  = (const float*)d_in[17];
  const float* ch_w2  = (const float*)d_in[18];
  const float* ch_b2  = (const float*)d_in[19];
  float* out = (float*)d_out;

  char* ws = (char*)d_ws;
  size_t off = 0;
  auto alloc = [&](size_t bytes) -> void* {
    void* p = ws + off;
    off += (bytes + 511) & ~(size_t)511;
    return p;
  };
  float* xw1   = (float*)alloc((size_t)NN * HH * 4);
  float* hbufs = (float*)alloc((size_t)7 * NN * HH * 4);
  float* h     = (float*)alloc((size_t)NN * HH * 4);
  float* h2    = (float*)alloc((size_t)NN * HH * 4);
  float* dinv  = (float*)alloc((size_t)NN * 4);
  int*   cnt   = (int*)alloc((size_t)NN * 4);
  int*   cursor= (int*)alloc((size_t)NN * 4);
  int*   offs  = (int*)alloc((size_t)(NN + 1) * 4);
  int*   csrc  = (int*)alloc((size_t)EE * 4);
  float* cnorm = (float*)alloc((size_t)EE * 4);

  gemm128_kernel<<<512, 128, 0, stream>>>(emb, convW1, xw1, NN);

  for (int t = 0; t < 7; ++t) {
    const int* es = edges + (size_t)t * 2 * EE;
    const int* ed = es + EE;
    zero2_kernel<<<(NN + 255) / 256, 256, 0, stream>>>(cnt, cursor, NN);
    count_kernel<<<(EE + 255) / 256, 256, 0, stream>>>(ed, cnt, EE);
    dinv_kernel<<<(NN + 255) / 256, 256, 0, stream>>>(cnt, dinv, NN);
    scan_kernel<<<1, 1024, 0, stream>>>(cnt, offs, NN);
    fillcsr_kernel<<<(EE + 255) / 256, 256, 0, stream>>>(es, ed, offs, cursor, dinv,
                                                         csrc, cnorm, EE);
    agg_kernel<<<NN, 128, 0, stream>>>(xw1, csrc, cnorm, offs, dinv, convb1, 1, h);
    gemm128_kernel<<<512, 128, 0, stream>>>(h, convW2, h2, NN);
    agg_kernel<<<NN, 128, 0, stream>>>(h2, csrc, cnorm, offs, dinv, convb2, 0,
                                       hbufs + (size_t)t * NN * HH);
    mask_kernel<<<(KK * HH + 255) / 256, 256, 0, stream>>>(
        node_t + (size_t)t * KK, hbufs + (size_t)t * NN * HH, KK);
  }

  // One fused launch: items [0, 7*NN) = (t=1..7, node); item 7*NN = (t=0, node 0)
  const int total_items = 7 * NN + 1;
  const int nwaves = 256 * 8;
  const int niter = (total_items + nwaves - 1) / nwaves;
  mixer11_kernel<<<256, 512, 0, stream>>>(hbufs, tn_g, tn_b, tok_w1, tok_b1, tok_w2,
                                          tok_b2, cn_g, cn_b, ch_w1, ch_b1, ch_w2, ch_b2,
                                          out, total_items, niter);
  bcast_kernel<<<((NN * HH - 128) + 255) / 256, 256, 0, stream>>>(out, NN * HH);
}

// Round 12
// 5503.751 us; speedup vs baseline: 1.1494x; 1.1043x over previous
//
#include <hip/hip_runtime.h>
#include <hip/hip_bf16.h>
#include <cstdint>
#include <cstddef>

#define NN 20000
#define HH 128
#define MM 16
#define KK 4000
#define EE 400000

typedef __attribute__((ext_vector_type(16))) float f16v;
typedef __attribute__((ext_vector_type(8))) short short8;   // MFMA A/B operand
typedef __attribute__((ext_vector_type(4))) float f32x4;    // MFMA accumulator
typedef __attribute__((ext_vector_type(8), may_alias)) short s8ma;
typedef __attribute__((ext_vector_type(4), may_alias)) float f4ma;
typedef __attribute__((ext_vector_type(2), may_alias)) float f2ma;

__device__ __forceinline__ float gelu_f(float x) {
  return 0.5f * x * (1.0f + erff(x * 0.70710678118654752440f));
}

__device__ __forceinline__ short f2bf(float f) {
  union { float f; unsigned u; } v; v.f = f;
  unsigned u = v.u;
  unsigned r = (u + 0x7FFFu + ((u >> 16) & 1u)) >> 16;  // RNE
  return (short)r;
}
__device__ __forceinline__ float bf2f(unsigned short s) {
  union { unsigned u; float f; } v; v.u = ((unsigned)s) << 16; return v.f;
}

// ---------------- GCN helper kernels (validated) ----------------

__global__ void zero2_kernel(int* __restrict__ a, int* __restrict__ b, int n) {
  int i = blockIdx.x * 256 + threadIdx.x;
  if (i < n) { a[i] = 0; b[i] = 0; }
}

__global__ void count_kernel(const int* __restrict__ dst, int* __restrict__ cnt, int n) {
  int e = blockIdx.x * 256 + threadIdx.x;
  if (e < n) atomicAdd(&cnt[dst[e]], 1);
}

__global__ void dinv_kernel(const int* __restrict__ cnt, float* __restrict__ dinv, int n) {
  int i = blockIdx.x * 256 + threadIdx.x;
  if (i < n) dinv[i] = rsqrtf((float)(cnt[i] + 1));
}

__global__ void scan_kernel(const int* __restrict__ cnt, int* __restrict__ offs, int n) {
  __shared__ int sh[1024];
  __shared__ int carry_s;
  int tid = threadIdx.x;
  if (tid == 0) carry_s = 0;
  __syncthreads();
  for (int base = 0; base < n; base += 1024) {
    int i = base + tid;
    int v = (i < n) ? cnt[i] : 0;
    sh[tid] = v;
    __syncthreads();
    for (int off = 1; off < 1024; off <<= 1) {
      int t = (tid >= off) ? sh[tid - off] : 0;
      __syncthreads();
      sh[tid] += t;
      __syncthreads();
    }
    int carry = carry_s;
    if (i < n) offs[i] = carry + sh[tid] - v;
    __syncthreads();
    if (tid == 1023) carry_s = carry + sh[1023];
    __syncthreads();
  }
  if (tid == 0) offs[n] = carry_s;
}

__global__ void fillcsr_kernel(const int* __restrict__ esrc, const int* __restrict__ edst,
                               const int* __restrict__ offs, int* __restrict__ cursor,
                               const float* __restrict__ dinv,
                               int* __restrict__ csrc, float* __restrict__ cnorm, int n) {
  int e = blockIdx.x * 256 + threadIdx.x;
  if (e < n) {
    int s = esrc[e], d = edst[e];
    int pos = offs[d] + atomicAdd(&cursor[d], 1);
    csrc[pos] = s;
    cnorm[pos] = dinv[s] * dinv[d];
  }
}

__global__ __launch_bounds__(128) void agg_kernel(const float* __restrict__ X,
    const int* __restrict__ csrc, const float* __restrict__ cnorm,
    const int* __restrict__ offs, const float* __restrict__ dinv,
    const float* __restrict__ bias, int relu, float* __restrict__ Y) {
  int i = blockIdx.x, c = threadIdx.x;
  float di = dinv[i];
  float acc = X[(size_t)i * HH + c] * di * di;
  int s = offs[i], e = offs[i + 1];
  for (int j = s; j < e; ++j) {
    acc += X[(size_t)csrc[j] * HH + c] * cnorm[j];
  }
  acc += bias[c];
  if (relu) acc = fmaxf(acc, 0.f);
  Y[(size_t)i * HH + c] = acc;
}

__global__ __launch_bounds__(128) void gemm128_kernel(const float* __restrict__ X,
    const float* __restrict__ W, float* __restrict__ Y, int nrows) {
  __shared__ float Ws[128 * 129];
  __shared__ float Xs[8 * 128];
  int tid = threadIdx.x;
  for (int idx = tid; idx < 16384; idx += 128) {
    int o = idx >> 7, k = idx & 127;
    Ws[o * 129 + k] = W[idx];
  }
  __syncthreads();
  for (int row0 = blockIdx.x * 8; row0 < nrows; row0 += gridDim.x * 8) {
    int nr = min(8, nrows - row0);
    for (int idx = tid; idx < nr * 128; idx += 128) Xs[idx] = X[(size_t)row0 * 128 + idx];
    __syncthreads();
    float acc[8] = {0, 0, 0, 0, 0, 0, 0, 0};
    for (int k = 0; k < 128; ++k) {
      float w = Ws[tid * 129 + k];
#pragma unroll
      for (int r = 0; r < 8; ++r) acc[r] += w * Xs[r * 128 + k];
    }
    for (int r = 0; r < nr; ++r) Y[(size_t)(row0 + r) * 128 + tid] = acc[r];
    __syncthreads();
  }
}

__global__ void mask_kernel(const int* __restrict__ nodes, float* __restrict__ H, int kn) {
  int idx = blockIdx.x * 256 + threadIdx.x;
  if (idx < kn * HH) {
    int j = idx >> 7, c = idx & 127;
    H[(size_t)nodes[j] * HH + c] = 0.f;
  }
}

__global__ void bcast_kernel(float* __restrict__ out, int total) {
  int idx = blockIdx.x * 256 + threadIdx.x + 128;
  if (idx < total) out[idx] = out[idx & 127];
}

// ---------------- mixer v12: round-1 block skeleton + MFMA channel-MLP ----------------
// 256 threads, ONE node per block-iteration (per-thread live state stays small —
// the clean-codegen class proven in round 1). Quantization set == validated v6
// (W bf16 only; activations f32; MFMA A = hi/lo bf16 split).
//   P1 row load + LN1 stats -> tile (x + mu,rs)        [16 thr/row]
//   P2 token-MLP f32 column-private + residual + colsum->fout  [threads<128]
//   P3 LN2 rows (cell-private in-place)                [16 thr/row]
//   P4 MFMA matmul1: wave w -> cols og in {2w,2w+1}; barrier; gelu->hidden in tile
//   P5 MFMA matmul2 + colsum via shfl + output write
// LDS 79.7 KB -> 2 blocks/CU possible.

__global__ __launch_bounds__(256) void mixer12_kernel(
    const float* __restrict__ hbufs,  // [7][NN][HH]
    const float* __restrict__ tn_g, const float* __restrict__ tn_b,
    const float* __restrict__ tok_w1, const float* __restrict__ tok_b1,
    const float* __restrict__ tok_w2, const float* __restrict__ tok_b2,
    const float* __restrict__ cn_g, const float* __restrict__ cn_b,
    const float* __restrict__ ch_w1, const float* __restrict__ ch_b1,
    const float* __restrict__ ch_w2, const float* __restrict__ ch_b2,
    float* __restrict__ out, int total_items, int niter) {
  __shared__ __align__(16) short W1f[16384];   // 32 KB B-fragments (bf16)
  __shared__ __align__(16) short W2f[16384];   // 32 KB
  __shared__ __align__(16) float zw[16 * 132]; // 8.45 KB node tile
  __shared__ float fout[128];                  // token-phase column sums
  __shared__ float tg[128], tbv[128], cg[128], cbv[128], cb1v[128], cb2v[128];
  __shared__ float tw1s[256], tw2s[256], tb1s[16], tb2s[16];

  const int tid = threadIdx.x;

  // B-fragment staging: frag f = og*256 + ks*64 + lane holds
  // W[og*16 + (lane&15)][ks*32 + (lane>>4)*8 + j], j=0..7 (bf16 RNE)
  for (int f = tid; f < 2048; f += 256) {
    int og = f >> 8, ks = (f >> 6) & 3, ln = f & 63;
    int o = og * 16 + (ln & 15);
    int k0 = ks * 32 + (ln >> 4) * 8;
    const float* s1 = ch_w1 + o * 128 + k0;
    const float* s2 = ch_w2 + o * 128 + k0;
    short8 p1, p2;
#pragma unroll
    for (int j = 0; j < 8; ++j) { p1[j] = f2bf(s1[j]); p2[j] = f2bf(s2[j]); }
    *(s8ma*)&W1f[f * 8] = (s8ma)p1;
    *(s8ma*)&W2f[f * 8] = (s8ma)p2;
  }
  if (tid < 128) {
    tg[tid] = tn_g[tid]; tbv[tid] = tn_b[tid];
    cg[tid] = cn_g[tid]; cbv[tid] = cn_b[tid];
    cb1v[tid] = ch_b1[tid]; cb2v[tid] = ch_b2[tid];
  }
  tw1s[tid] = tok_w1[tid & 255];
  tw2s[tid] = tok_w2[tid & 255];
  if (tid < 16) { tb1s[tid] = tok_b1[tid]; tb2s[tid] = tok_b2[tid]; }
  __syncthreads();

  const int lr = tid >> 4;        // row 0..15 (P1/P3)
  const int lq = tid & 15;        // sub-slot: 8 channels each
  const int lane = tid & 63;
  const int wv = tid >> 6;        // wave 0..3 -> og pair {2wv, 2wv+1}
  const int q = lane >> 4;
  const int h = lane & 15;

  for (int it = 0; it < niter; ++it) {
    const int item = (size_t)it * gridDim.x + blockIdx.x;
    const bool active = item < total_items;
    int t = 0, node = 0;
    if (active && item < 7 * NN) { t = item / NN + 1; node = item % NN; }

    // ---- P1: load row lr (8 floats per thread) + LN1 stats -> tile ----
    {
      f4ma xa, xb;
      int src_t = lr - (MM - t);
      if (active && src_t >= 0) {
        const float* hp = hbufs + ((size_t)src_t * NN + node) * HH + lq * 8;
        xa = *(const f4ma*)hp;
        xb = *(const f4ma*)(hp + 4);
      } else {
        xa = (f4ma){0.f, 0.f, 0.f, 0.f};
        xb = (f4ma){0.f, 0.f, 0.f, 0.f};
      }
      float s = xa.x + xa.y + xa.z + xa.w + xb.x + xb.y + xb.z + xb.w;
      float ss = xa.x * xa.x + xa.y * xa.y + xa.z * xa.z + xa.w * xa.w +
                 xb.x * xb.x + xb.y * xb.y + xb.z * xb.z + xb.w * xb.w;
#pragma unroll
      for (int d = 1; d < 16; d <<= 1) { s += __shfl_xor(s, d); ss += __shfl_xor(ss, d); }
      float mu = s * (1.f / 128.f);
      float var = fmaxf(ss * (1.f / 128.f) - mu * mu, 0.f);
      float rs = rsqrtf(var + 1e-5f);
      *(f4ma*)&zw[lr * 132 + lq * 8] = xa;
      *(f4ma*)&zw[lr * 132 + lq * 8 + 4] = xb;
      if (lq == 0) { zw[lr * 132 + 128] = mu; zw[lr * 132 + 129] = rs; }
    }
    __syncthreads();   // (1)

    // ---- P2: token-MLP f32, column-private (threads < 128) ----
    if (tid < 128) {
      const int c = tid;
      const float tg0 = tg[c], tb0 = tbv[c];
      f16v xv, av;
#pragma unroll
      for (int hd = 0; hd < 16; ++hd) av[hd] = tb1s[hd];
#pragma unroll
      for (int r = 0; r < 16; ++r) {
        float xvr = zw[r * 132 + c];
        float mu = zw[r * 132 + 128];
        float rs = zw[r * 132 + 129];
        xv[r] = xvr;
        float z = (xvr - mu) * rs * tg0 + tb0;
#pragma unroll
        for (int hd = 0; hd < 16; ++hd) av[hd] += tw1s[hd * 16 + r] * z;
      }
#pragma unroll
      for (int hd = 0; hd < 16; ++hd) av[hd] = gelu_f(av[hd]);
      float cs = 0.f;
#pragma unroll
      for (int r = 0; r < 16; ++r) {
        float o = tb2s[r];
#pragma unroll
        for (int hd = 0; hd < 16; ++hd) o += tw2s[r * 16 + hd] * av[hd];
        float nx = xv[r] + o;
        cs += nx;
        zw[r * 132 + c] = nx;
      }
      fout[c] = cs;
    }
    __syncthreads();   // (2)

    // ---- P3: LN2 rows, cell-private in-place ----
    {
      f4ma xa = *(const f4ma*)&zw[lr * 132 + lq * 8];
      f4ma xb = *(const f4ma*)&zw[lr * 132 + lq * 8 + 4];
      float s = xa.x + xa.y + xa.z + xa.w + xb.x + xb.y + xb.z + xb.w;
      float ss = xa.x * xa.x + xa.y * xa.y + xa.z * xa.z + xa.w * xa.w +
                 xb.x * xb.x + xb.y * xb.y + xb.z * xb.z + xb.w * xb.w;
#pragma unroll
      for (int d = 1; d < 16; d <<= 1) { s += __shfl_xor(s, d); ss += __shfl_xor(ss, d); }
      float mu = s * (1.f / 128.f);
      float var = fmaxf(ss * (1.f / 128.f) - mu * mu, 0.f);
      float rs = rsqrtf(var + 1e-5f);
      int c0 = lq * 8;
      f4ma za, zb;
      za.x = (xa.x - mu) * rs * cg[c0]     + cbv[c0];
      za.y = (xa.y - mu) * rs * cg[c0 + 1] + cbv[c0 + 1];
      za.z = (xa.z - mu) * rs * cg[c0 + 2] + cbv[c0 + 2];
      za.w = (xa.w - mu) * rs * cg[c0 + 3] + cbv[c0 + 3];
      zb.x = (xb.x - mu) * rs * cg[c0 + 4] + cbv[c0 + 4];
      zb.y = (xb.y - mu) * rs * cg[c0 + 5] + cbv[c0 + 5];
      zb.z = (xb.z - mu) * rs * cg[c0 + 6] + cbv[c0 + 6];
      zb.w = (xb.w - mu) * rs * cg[c0 + 7] + cbv[c0 + 7];
      *(f4ma*)&zw[lr * 132 + c0] = za;
      *(f4ma*)&zw[lr * 132 + c0 + 4] = zb;
    }
    __syncthreads();   // (3)

    // ---- P4: MFMA matmul1 -> hidden (wave wv owns cols og = 2wv, 2wv+1) ----
    {
      f32x4 acc0, acc1;
      {
        float b0 = cb1v[(2 * wv) * 16 + h];
        float b1 = cb1v[(2 * wv + 1) * 16 + h];
        acc0 = (f32x4){b0, b0, b0, b0};
        acc1 = (f32x4){b1, b1, b1, b1};
      }
#pragma unroll
      for (int ks = 0; ks < 4; ++ks) {
        f4ma v0 = *(const f4ma*)&zw[h * 132 + ks * 32 + q * 8];
        f4ma v1 = *(const f4ma*)&zw[h * 132 + ks * 32 + q * 8 + 4];
        float e[8] = {v0.x, v0.y, v0.z, v0.w, v1.x, v1.y, v1.z, v1.w};
        short8 ah, al;
#pragma unroll
        for (int j = 0; j < 8; ++j) {
          short hi = f2bf(e[j]);
          ah[j] = hi;
          al[j] = f2bf(e[j] - bf2f((unsigned short)hi));
        }
        short8 b0 = (short8)(*(const s8ma*)&W1f[((2 * wv) * 256 + ks * 64 + lane) * 8]);
        short8 b1 = (short8)(*(const s8ma*)&W1f[((2 * wv + 1) * 256 + ks * 64 + lane) * 8]);
        acc0 = __builtin_amdgcn_mfma_f32_16x16x32_bf16(ah, b0, acc0, 0, 0, 0);
        acc0 = __builtin_amdgcn_mfma_f32_16x16x32_bf16(al, b0, acc0, 0, 0, 0);
        acc1 = __builtin_amdgcn_mfma_f32_16x16x32_bf16(ah, b1, acc1, 0, 0, 0);
        acc1 = __builtin_amdgcn_mfma_f32_16x16x32_bf16(al, b1, acc1, 0, 0, 0);
      }
      __syncthreads();   // (4) all A reads of z2 done before hidden overwrite
      // D layout: row = q*4+rg, col = og*16+h
#pragma unroll
      for (int rg = 0; rg < 4; ++rg) {
        zw[(q * 4 + rg) * 132 + (2 * wv) * 16 + h]     = gelu_f(acc0[rg]);
        zw[(q * 4 + rg) * 132 + (2 * wv + 1) * 16 + h] = gelu_f(acc1[rg]);
      }
    }
    __syncthreads();   // (5) hidden visible

    // ---- P5: MFMA matmul2 + column sums + output ----
    {
      f32x4 acc0, acc1;
      {
        float b0 = cb2v[(2 * wv) * 16 + h];
        float b1 = cb2v[(2 * wv + 1) * 16 + h];
        acc0 = (f32x4){b0, b0, b0, b0};
        acc1 = (f32x4){b1, b1, b1, b1};
      }
#pragma unroll
      for (int ks = 0; ks < 4; ++ks) {
        f4ma v0 = *(const f4ma*)&zw[h * 132 + ks * 32 + q * 8];
        f4ma v1 = *(const f4ma*)&zw[h * 132 + ks * 32 + q * 8 + 4];
        float e[8] = {v0.x, v0.y, v0.z, v0.w, v1.x, v1.y, v1.z, v1.w};
        short8 ah, al;
#pragma unroll
        for (int j = 0; j < 8; ++j) {
          short hi = f2bf(e[j]);
          ah[j] = hi;
          al[j] = f2bf(e[j] - bf2f((unsigned short)hi));
        }
        short8 b0 = (short8)(*(const s8ma*)&W2f[((2 * wv) * 256 + ks * 64 + lane) * 8]);
        short8 b1 = (short8)(*(const s8ma*)&W2f[((2 * wv + 1) * 256 + ks * 64 + lane) * 8]);
        acc0 = __builtin_amdgcn_mfma_f32_16x16x32_bf16(ah, b0, acc0, 0, 0, 0);
        acc0 = __builtin_amdgcn_mfma_f32_16x16x32_bf16(al, b0, acc0, 0, 0, 0);
        acc1 = __builtin_amdgcn_mfma_f32_16x16x32_bf16(ah, b1, acc1, 0, 0, 0);
        acc1 = __builtin_amdgcn_mfma_f32_16x16x32_bf16(al, b1, acc1, 0, 0, 0);
      }
      float v0s = acc0[0] + acc0[1] + acc0[2] + acc0[3];
      float v1s = acc1[0] + acc1[1] + acc1[2] + acc1[3];
      v0s += __shfl_xor(v0s, 16); v0s += __shfl_xor(v0s, 32);
      v1s += __shfl_xor(v1s, 16); v1s += __shfl_xor(v1s, 32);
      if (q == 0 && active) {
        int c0 = (2 * wv) * 16 + h;
        int c1 = (2 * wv + 1) * 16 + h;
        size_t base = ((size_t)t * NN + node) * HH;
        out[base + c0] = (fout[c0] + v0s) * (1.f / 16.f);
        out[base + c1] = (fout[c1] + v1s) * (1.f / 16.f);
      }
    }
    __syncthreads();   // (6) tile + fout reuse next iteration
  }
}

// ---------------- launch ----------------

extern "C" void kernel_launch(void* const* d_in, const int* in_sizes, int n_in,
                              void* d_out, int out_size, void* d_ws, size_t ws_size,
                              hipStream_t stream) {
  const int* node_t   = (const int*)d_in[0];
  const int* edges    = (const int*)d_in[1];
  const float* emb    = (const float*)d_in[3];
  const float* convW1 = (const float*)d_in[4];
  const float* convb1 = (const float*)d_in[5];
  const float* convW2 = (const float*)d_in[6];
  const float* convb2 = (const float*)d_in[7];
  const float* tn_g   = (const float*)d_in[8];
  const float* tn_b   = (const float*)d_in[9];
  const float* tok_w1 = (const float*)d_in[10];
  const float* tok_b1 = (const float*)d_in[11];
  const float* tok_w2 = (const float*)d_in[12];
  const float* tok_b2 = (const float*)d_in[13];
  const float* cn_g   = (const float*)d_in[14];
  const float* cn_b   = (const float*)d_in[15];
  const float* ch_w1  = (const float*)d_in[16];
  const float* ch_b1  = (const float*)d_in[17];
  const float* ch_w2  = (const float*)d_in[18];
  const float* ch_b2  = (const float*)d_in[19];
  float* out = (float*)d_out;

  char* ws = (char*)d_ws;
  size_t off = 0;
  auto alloc = [&](size_t bytes) -> void* {
    void* p = ws + off;
    off += (bytes + 511) & ~(size_t)511;
    return p;
  };
  float* xw1   = (float*)alloc((size_t)NN * HH * 4);
  float* hbufs = (float*)alloc((size_t)7 * NN * HH * 4);
  float* h     = (float*)alloc((size_t)NN * HH * 4);
  float* h2    = (float*)alloc((size_t)NN * HH * 4);
  float* dinv  = (float*)alloc((size_t)NN * 4);
  int*   cnt   = (int*)alloc((size_t)NN * 4);
  int*   cursor= (int*)alloc((size_t)NN * 4);
  int*   offs  = (int*)alloc((size_t)(NN + 1) * 4);
  int*   csrc  = (int*)alloc((size_t)EE * 4);
  float* cnorm = (float*)alloc((size_t)EE * 4);

  gemm128_kernel<<<512, 128, 0, stream>>>(emb, convW1, xw1, NN);

  for (int t = 0; t < 7; ++t) {
    const int* es = edges + (size_t)t * 2 * EE;
    const int* ed = es + EE;
    zero2_kernel<<<(NN + 255) / 256, 256, 0, stream>>>(cnt, cursor, NN);
    count_kernel<<<(EE + 255) / 256, 256, 0, stream>>>(ed, cnt, EE);
    dinv_kernel<<<(NN + 255) / 256, 256, 0, stream>>>(cnt, dinv, NN);
    scan_kernel<<<1, 1024, 0, stream>>>(cnt, offs, NN);
    fillcsr_kernel<<<(EE + 255) / 256, 256, 0, stream>>>(es, ed, offs, cursor, dinv,
                                                         csrc, cnorm, EE);
    agg_kernel<<<NN, 128, 0, stream>>>(xw1, csrc, cnorm, offs, dinv, convb1, 1, h);
    gemm128_kernel<<<512, 128, 0, stream>>>(h, convW2, h2, NN);
    agg_kernel<<<NN, 128, 0, stream>>>(h2, csrc, cnorm, offs, dinv, convb2, 0,
                                       hbufs + (size_t)t * NN * HH);
    mask_kernel<<<(KK * HH + 255) / 256, 256, 0, stream>>>(
        node_t + (size_t)t * KK, hbufs + (size_t)t * NN * HH, KK);
  }

  // One fused launch: items [0, 7*NN) = (t=1..7, node); item 7*NN = (t=0, node 0)
  const int total_items = 7 * NN + 1;
  const int nblocks = 512;
  const int niter = (total_items + nblocks - 1) / nblocks;
  mixer12_kernel<<<nblocks, 256, 0, stream>>>(hbufs, tn_g, tn_b, tok_w1, tok_b1, tok_w2,
                                              tok_b2, cn_g, cn_b, ch_w1, ch_b1, ch_w2,
                                              ch_b2, out, total_items, niter);
  bcast_kernel<<<((NN * HH - 128) + 255) / 256, 256, 0, stream>>>(out, NN * HH);
}

// Round 13
// 5338.068 us; speedup vs baseline: 1.1851x; 1.0310x over previous
//
#include <hip/hip_runtime.h>
#include <hip/hip_bf16.h>
#include <cstdint>
#include <cstddef>

#define NN 20000
#define HH 128
#define MM 16
#define KK 4000
#define EE 400000

typedef __attribute__((ext_vector_type(16))) float f16v;
typedef __attribute__((ext_vector_type(8))) short short8;   // MFMA A/B operand
typedef __attribute__((ext_vector_type(4))) float f32x4;    // MFMA accumulator
typedef __attribute__((ext_vector_type(8), may_alias)) short s8ma;
typedef __attribute__((ext_vector_type(4), may_alias)) float f4ma;
typedef __attribute__((ext_vector_type(2), may_alias)) float f2ma;

__device__ __forceinline__ float gelu_f(float x) {
  return 0.5f * x * (1.0f + erff(x * 0.70710678118654752440f));
}

__device__ __forceinline__ short f2bf(float f) {
  union { float f; unsigned u; } v; v.f = f;
  unsigned u = v.u;
  unsigned r = (u + 0x7FFFu + ((u >> 16) & 1u)) >> 16;  // RNE
  return (short)r;
}
__device__ __forceinline__ float bf2f(unsigned short s) {
  union { unsigned u; float f; } v; v.u = ((unsigned)s) << 16; return v.f;
}

// ---------------- GCN helper kernels (validated) ----------------

__global__ void zero2_kernel(int* __restrict__ a, int* __restrict__ b, int n) {
  int i = blockIdx.x * 256 + threadIdx.x;
  if (i < n) { a[i] = 0; b[i] = 0; }
}

__global__ void count_kernel(const int* __restrict__ dst, int* __restrict__ cnt, int n) {
  int e = blockIdx.x * 256 + threadIdx.x;
  if (e < n) atomicAdd(&cnt[dst[e]], 1);
}

__global__ void dinv_kernel(const int* __restrict__ cnt, float* __restrict__ dinv, int n) {
  int i = blockIdx.x * 256 + threadIdx.x;
  if (i < n) dinv[i] = rsqrtf((float)(cnt[i] + 1));
}

__global__ void scan_kernel(const int* __restrict__ cnt, int* __restrict__ offs, int n) {
  __shared__ int sh[1024];
  __shared__ int carry_s;
  int tid = threadIdx.x;
  if (tid == 0) carry_s = 0;
  __syncthreads();
  for (int base = 0; base < n; base += 1024) {
    int i = base + tid;
    int v = (i < n) ? cnt[i] : 0;
    sh[tid] = v;
    __syncthreads();
    for (int off = 1; off < 1024; off <<= 1) {
      int t = (tid >= off) ? sh[tid - off] : 0;
      __syncthreads();
      sh[tid] += t;
      __syncthreads();
    }
    int carry = carry_s;
    if (i < n) offs[i] = carry + sh[tid] - v;
    __syncthreads();
    if (tid == 1023) carry_s = carry + sh[1023];
    __syncthreads();
  }
  if (tid == 0) offs[n] = carry_s;
}

__global__ void fillcsr_kernel(const int* __restrict__ esrc, const int* __restrict__ edst,
                               const int* __restrict__ offs, int* __restrict__ cursor,
                               const float* __restrict__ dinv,
                               int* __restrict__ csrc, float* __restrict__ cnorm, int n) {
  int e = blockIdx.x * 256 + threadIdx.x;
  if (e < n) {
    int s = esrc[e], d = edst[e];
    int pos = offs[d] + atomicAdd(&cursor[d], 1);
    csrc[pos] = s;
    cnorm[pos] = dinv[s] * dinv[d];
  }
}

__global__ __launch_bounds__(128) void agg_kernel(const float* __restrict__ X,
    const int* __restrict__ csrc, const float* __restrict__ cnorm,
    const int* __restrict__ offs, const float* __restrict__ dinv,
    const float* __restrict__ bias, int relu, float* __restrict__ Y) {
  int i = blockIdx.x, c = threadIdx.x;
  float di = dinv[i];
  float acc = X[(size_t)i * HH + c] * di * di;
  int s = offs[i], e = offs[i + 1];
  for (int j = s; j < e; ++j) {
    acc += X[(size_t)csrc[j] * HH + c] * cnorm[j];
  }
  acc += bias[c];
  if (relu) acc = fmaxf(acc, 0.f);
  Y[(size_t)i * HH + c] = acc;
}

__global__ __launch_bounds__(128) void gemm128_kernel(const float* __restrict__ X,
    const float* __restrict__ W, float* __restrict__ Y, int nrows) {
  __shared__ float Ws[128 * 129];
  __shared__ float Xs[8 * 128];
  int tid = threadIdx.x;
  for (int idx = tid; idx < 16384; idx += 128) {
    int o = idx >> 7, k = idx & 127;
    Ws[o * 129 + k] = W[idx];
  }
  __syncthreads();
  for (int row0 = blockIdx.x * 8; row0 < nrows; row0 += gridDim.x * 8) {
    int nr = min(8, nrows - row0);
    for (int idx = tid; idx < nr * 128; idx += 128) Xs[idx] = X[(size_t)row0 * 128 + idx];
    __syncthreads();
    float acc[8] = {0, 0, 0, 0, 0, 0, 0, 0};
    for (int k = 0; k < 128; ++k) {
      float w = Ws[tid * 129 + k];
#pragma unroll
      for (int r = 0; r < 8; ++r) acc[r] += w * Xs[r * 128 + k];
    }
    for (int r = 0; r < nr; ++r) Y[(size_t)(row0 + r) * 128 + tid] = acc[r];
    __syncthreads();
  }
}

__global__ void mask_kernel(const int* __restrict__ nodes, float* __restrict__ H, int kn) {
  int idx = blockIdx.x * 256 + threadIdx.x;
  if (idx < kn * HH) {
    int j = idx >> 7, c = idx & 127;
    H[(size_t)nodes[j] * HH + c] = 0.f;
  }
}

__global__ void bcast_kernel(float* __restrict__ out, int total) {
  int idx = blockIdx.x * 256 + threadIdx.x + 128;
  if (idx < total) out[idx] = out[idx & 127];
}

// ---------------- mixer v13: v12 with W fragments in REGISTERS ----------------
// v12 proved the block skeleton is codegen-clean (VGPR 168, zero scratch) but
// occupancy-starved (80KB LDS -> 1 block/CU, 4 waves). Each wave only ever uses
// 16 wave-constant B-fragments (2 cols x 4 ks x 2 matrices = 64 VGPRs): load
// them ONCE from global into registers, drop the 64KB W LDS staging entirely.
// LDS 80 -> 14 KB; occupancy VGPR-bound (~2-3 blocks/CU). Math identical to v12.

__global__ __launch_bounds__(256) void mixer13_kernel(
    const float* __restrict__ hbufs,  // [7][NN][HH]
    const float* __restrict__ tn_g, const float* __restrict__ tn_b,
    const float* __restrict__ tok_w1, const float* __restrict__ tok_b1,
    const float* __restrict__ tok_w2, const float* __restrict__ tok_b2,
    const float* __restrict__ cn_g, const float* __restrict__ cn_b,
    const float* __restrict__ ch_w1, const float* __restrict__ ch_b1,
    const float* __restrict__ ch_w2, const float* __restrict__ ch_b2,
    float* __restrict__ out, int total_items, int niter) {
  __shared__ __align__(16) float zw[16 * 132]; // 8.45 KB node tile
  __shared__ float fout[128];                  // token-phase column sums
  __shared__ float tg[128], tbv[128], cg[128], cbv[128], cb1v[128], cb2v[128];
  __shared__ float tw1s[256], tw2s[256], tb1s[16], tb2s[16];

  const int tid = threadIdx.x;
  const int lr = tid >> 4;        // row 0..15 (P1/P3)
  const int lq = tid & 15;        // sub-slot: 8 channels each
  const int lane = tid & 63;
  const int wv = tid >> 6;        // wave 0..3 -> og pair {2wv, 2wv+1}
  const int q = lane >> 4;
  const int h = lane & 15;

  if (tid < 128) {
    tg[tid] = tn_g[tid]; tbv[tid] = tn_b[tid];
    cg[tid] = cn_g[tid]; cbv[tid] = cn_b[tid];
    cb1v[tid] = ch_b1[tid]; cb2v[tid] = ch_b2[tid];
  }
  tw1s[tid] = tok_w1[tid & 255];
  tw2s[tid] = tok_w2[tid & 255];
  if (tid < 16) { tb1s[tid] = tok_b1[tid]; tb2s[tid] = tok_b2[tid]; }

  // Wave-constant B-fragments in registers (indices compile-time after unroll):
  // wf[ks][j] holds W[(2wv+j)*16 + h][ks*32 + q*8 .. +7] as bf16.
  short8 wf1[4][2], wf2[4][2];
#pragma unroll
  for (int ks = 0; ks < 4; ++ks) {
#pragma unroll
    for (int j = 0; j < 2; ++j) {
      int o = (2 * wv + j) * 16 + h;
      int k0 = ks * 32 + q * 8;
      const float* s1 = ch_w1 + o * 128 + k0;
      const float* s2 = ch_w2 + o * 128 + k0;
      short8 p1, p2;
#pragma unroll
      for (int e = 0; e < 8; ++e) { p1[e] = f2bf(s1[e]); p2[e] = f2bf(s2[e]); }
      wf1[ks][j] = p1;
      wf2[ks][j] = p2;
    }
  }
  __syncthreads();

  for (int it = 0; it < niter; ++it) {
    const int item = (size_t)it * gridDim.x + blockIdx.x;
    const bool active = item < total_items;
    int t = 0, node = 0;
    if (active && item < 7 * NN) { t = item / NN + 1; node = item % NN; }

    // ---- P1: load row lr (8 floats per thread) + LN1 stats -> tile ----
    {
      f4ma xa, xb;
      int src_t = lr - (MM - t);
      if (active && src_t >= 0) {
        const float* hp = hbufs + ((size_t)src_t * NN + node) * HH + lq * 8;
        xa = *(const f4ma*)hp;
        xb = *(const f4ma*)(hp + 4);
      } else {
        xa = (f4ma){0.f, 0.f, 0.f, 0.f};
        xb = (f4ma){0.f, 0.f, 0.f, 0.f};
      }
      float s = xa.x + xa.y + xa.z + xa.w + xb.x + xb.y + xb.z + xb.w;
      float ss = xa.x * xa.x + xa.y * xa.y + xa.z * xa.z + xa.w * xa.w +
                 xb.x * xb.x + xb.y * xb.y + xb.z * xb.z + xb.w * xb.w;
#pragma unroll
      for (int d = 1; d < 16; d <<= 1) { s += __shfl_xor(s, d); ss += __shfl_xor(ss, d); }
      float mu = s * (1.f / 128.f);
      float var = fmaxf(ss * (1.f / 128.f) - mu * mu, 0.f);
      float rs = rsqrtf(var + 1e-5f);
      *(f4ma*)&zw[lr * 132 + lq * 8] = xa;
      *(f4ma*)&zw[lr * 132 + lq * 8 + 4] = xb;
      if (lq == 0) { zw[lr * 132 + 128] = mu; zw[lr * 132 + 129] = rs; }
    }
    __syncthreads();   // (1)

    // ---- P2: token-MLP f32, column-private (threads < 128) ----
    if (tid < 128) {
      const int c = tid;
      const float tg0 = tg[c], tb0 = tbv[c];
      f16v xv, av;
#pragma unroll
      for (int hd = 0; hd < 16; ++hd) av[hd] = tb1s[hd];
#pragma unroll
      for (int r = 0; r < 16; ++r) {
        float xvr = zw[r * 132 + c];
        float mu = zw[r * 132 + 128];
        float rs = zw[r * 132 + 129];
        xv[r] = xvr;
        float z = (xvr - mu) * rs * tg0 + tb0;
#pragma unroll
        for (int hd = 0; hd < 16; ++hd) av[hd] += tw1s[hd * 16 + r] * z;
      }
#pragma unroll
      for (int hd = 0; hd < 16; ++hd) av[hd] = gelu_f(av[hd]);
      float cs = 0.f;
#pragma unroll
      for (int r = 0; r < 16; ++r) {
        float o = tb2s[r];
#pragma unroll
        for (int hd = 0; hd < 16; ++hd) o += tw2s[r * 16 + hd] * av[hd];
        float nx = xv[r] + o;
        cs += nx;
        zw[r * 132 + c] = nx;
      }
      fout[c] = cs;
    }
    __syncthreads();   // (2)

    // ---- P3: LN2 rows, cell-private in-place ----
    {
      f4ma xa = *(const f4ma*)&zw[lr * 132 + lq * 8];
      f4ma xb = *(const f4ma*)&zw[lr * 132 + lq * 8 + 4];
      float s = xa.x + xa.y + xa.z + xa.w + xb.x + xb.y + xb.z + xb.w;
      float ss = xa.x * xa.x + xa.y * xa.y + xa.z * xa.z + xa.w * xa.w +
                 xb.x * xb.x + xb.y * xb.y + xb.z * xb.z + xb.w * xb.w;
#pragma unroll
      for (int d = 1; d < 16; d <<= 1) { s += __shfl_xor(s, d); ss += __shfl_xor(ss, d); }
      float mu = s * (1.f / 128.f);
      float var = fmaxf(ss * (1.f / 128.f) - mu * mu, 0.f);
      float rs = rsqrtf(var + 1e-5f);
      int c0 = lq * 8;
      f4ma za, zb;
      za.x = (xa.x - mu) * rs * cg[c0]     + cbv[c0];
      za.y = (xa.y - mu) * rs * cg[c0 + 1] + cbv[c0 + 1];
      za.z = (xa.z - mu) * rs * cg[c0 + 2] + cbv[c0 + 2];
      za.w = (xa.w - mu) * rs * cg[c0 + 3] + cbv[c0 + 3];
      zb.x = (xb.x - mu) * rs * cg[c0 + 4] + cbv[c0 + 4];
      zb.y = (xb.y - mu) * rs * cg[c0 + 5] + cbv[c0 + 5];
      zb.z = (xb.z - mu) * rs * cg[c0 + 6] + cbv[c0 + 6];
      zb.w = (xb.w - mu) * rs * cg[c0 + 7] + cbv[c0 + 7];
      *(f4ma*)&zw[lr * 132 + c0] = za;
      *(f4ma*)&zw[lr * 132 + c0 + 4] = zb;
    }
    __syncthreads();   // (3)

    // ---- P4: MFMA matmul1 -> hidden (wave wv owns cols og = 2wv, 2wv+1) ----
    {
      f32x4 acc0, acc1;
      {
        float b0 = cb1v[(2 * wv) * 16 + h];
        float b1 = cb1v[(2 * wv + 1) * 16 + h];
        acc0 = (f32x4){b0, b0, b0, b0};
        acc1 = (f32x4){b1, b1, b1, b1};
      }
#pragma unroll
      for (int ks = 0; ks < 4; ++ks) {
        f4ma v0 = *(const f4ma*)&zw[h * 132 + ks * 32 + q * 8];
        f4ma v1 = *(const f4ma*)&zw[h * 132 + ks * 32 + q * 8 + 4];
        float e[8] = {v0.x, v0.y, v0.z, v0.w, v1.x, v1.y, v1.z, v1.w};
        short8 ah, al;
#pragma unroll
        for (int j = 0; j < 8; ++j) {
          short hi = f2bf(e[j]);
          ah[j] = hi;
          al[j] = f2bf(e[j] - bf2f((unsigned short)hi));
        }
        acc0 = __builtin_amdgcn_mfma_f32_16x16x32_bf16(ah, wf1[ks][0], acc0, 0, 0, 0);
        acc0 = __builtin_amdgcn_mfma_f32_16x16x32_bf16(al, wf1[ks][0], acc0, 0, 0, 0);
        acc1 = __builtin_amdgcn_mfma_f32_16x16x32_bf16(ah, wf1[ks][1], acc1, 0, 0, 0);
        acc1 = __builtin_amdgcn_mfma_f32_16x16x32_bf16(al, wf1[ks][1], acc1, 0, 0, 0);
      }
      __syncthreads();   // (4) all A reads of z2 done before hidden overwrite
      // D layout: row = q*4+rg, col = og*16+h
#pragma unroll
      for (int rg = 0; rg < 4; ++rg) {
        zw[(q * 4 + rg) * 132 + (2 * wv) * 16 + h]     = gelu_f(acc0[rg]);
        zw[(q * 4 + rg) * 132 + (2 * wv + 1) * 16 + h] = gelu_f(acc1[rg]);
      }
    }
    __syncthreads();   // (5) hidden visible

    // ---- P5: MFMA matmul2 + column sums + output ----
    {
      f32x4 acc0, acc1;
      {
        float b0 = cb2v[(2 * wv) * 16 + h];
        float b1 = cb2v[(2 * wv + 1) * 16 + h];
        acc0 = (f32x4){b0, b0, b0, b0};
        acc1 = (f32x4){b1, b1, b1, b1};
      }
#pragma unroll
      for (int ks = 0; ks < 4; ++ks) {
        f4ma v0 = *(const f4ma*)&zw[h * 132 + ks * 32 + q * 8];
        f4ma v1 = *(const f4ma*)&zw[h * 132 + ks * 32 + q * 8 + 4];
        float e[8] = {v0.x, v0.y, v0.z, v0.w, v1.x, v1.y, v1.z, v1.w};
        short8 ah, al;
#pragma unroll
        for (int j = 0; j < 8; ++j) {
          short hi = f2bf(e[j]);
          ah[j] = hi;
          al[j] = f2bf(e[j] - bf2f((unsigned short)hi));
        }
        acc0 = __builtin_amdgcn_mfma_f32_16x16x32_bf16(ah, wf2[ks][0], acc0, 0, 0, 0);
        acc0 = __builtin_amdgcn_mfma_f32_16x16x32_bf16(al, wf2[ks][0], acc0, 0, 0, 0);
        acc1 = __builtin_amdgcn_mfma_f32_16x16x32_bf16(ah, wf2[ks][1], acc1, 0, 0, 0);
        acc1 = __builtin_amdgcn_mfma_f32_16x16x32_bf16(al, wf2[ks][1], acc1, 0, 0, 0);
      }
      float v0s = acc0[0] + acc0[1] + acc0[2] + acc0[3];
      float v1s = acc1[0] + acc1[1] + acc1[2] + acc1[3];
      v0s += __shfl_xor(v0s, 16); v0s += __shfl_xor(v0s, 32);
      v1s += __shfl_xor(v1s, 16); v1s += __shfl_xor(v1s, 32);
      if (q == 0 && active) {
        int c0 = (2 * wv) * 16 + h;
        int c1 = (2 * wv + 1) * 16 + h;
        size_t base = ((size_t)t * NN + node) * HH;
        out[base + c0] = (fout[c0] + v0s) * (1.f / 16.f);
        out[base + c1] = (fout[c1] + v1s) * (1.f / 16.f);
      }
    }
    __syncthreads();   // (6) tile + fout reuse next iteration
  }
}

// ---------------- launch ----------------

extern "C" void kernel_launch(void* const* d_in, const int* in_sizes, int n_in,
                              void* d_out, int out_size, void* d_ws, size_t ws_size,
                              hipStream_t stream) {
  const int* node_t   = (const int*)d_in[0];
  const int* edges    = (const int*)d_in[1];
  const float* emb    = (const float*)d_in[3];
  const float* convW1 = (const float*)d_in[4];
  const float* convb1 = (const float*)d_in[5];
  const float* convW2 = (const float*)d_in[6];
  const float* convb2 = (const float*)d_in[7];
  const float* tn_g   = (const float*)d_in[8];
  const float* tn_b   = (const float*)d_in[9];
  const float* tok_w1 = (const float*)d_in[10];
  const float* tok_b1 = (const float*)d_in[11];
  const float* tok_w2 = (const float*)d_in[12];
  const float* tok_b2 = (const float*)d_in[13];
  const float* cn_g   = (const float*)d_in[14];
  const float* cn_b   = (const float*)d_in[15];
  const float* ch_w1  = (const float*)d_in[16];
  const float* ch_b1  = (const float*)d_in[17];
  const float* ch_w2  = (const float*)d_in[18];
  const float* ch_b2  = (const float*)d_in[19];
  float* out = (float*)d_out;

  char* ws = (char*)d_ws;
  size_t off = 0;
  auto alloc = [&](size_t bytes) -> void* {
    void* p = ws + off;
    off += (bytes + 511) & ~(size_t)511;
    return p;
  };
  float* xw1   = (float*)alloc((size_t)NN * HH * 4);
  float* hbufs = (float*)alloc((size_t)7 * NN * HH * 4);
  float* h     = (float*)alloc((size_t)NN * HH * 4);
  float* h2    = (float*)alloc((size_t)NN * HH * 4);
  float* dinv  = (float*)alloc((size_t)NN * 4);
  int*   cnt   = (int*)alloc((size_t)NN * 4);
  int*   cursor= (int*)alloc((size_t)NN * 4);
  int*   offs  = (int*)alloc((size_t)(NN + 1) * 4);
  int*   csrc  = (int*)alloc((size_t)EE * 4);
  float* cnorm = (float*)alloc((size_t)EE * 4);

  gemm128_kernel<<<512, 128, 0, stream>>>(emb, convW1, xw1, NN);

  for (int t = 0; t < 7; ++t) {
    const int* es = edges + (size_t)t * 2 * EE;
    const int* ed = es + EE;
    zero2_kernel<<<(NN + 255) / 256, 256, 0, stream>>>(cnt, cursor, NN);
    count_kernel<<<(EE + 255) / 256, 256, 0, stream>>>(ed, cnt, EE);
    dinv_kernel<<<(NN + 255) / 256, 256, 0, stream>>>(cnt, dinv, NN);
    scan_kernel<<<1, 1024, 0, stream>>>(cnt, offs, NN);
    fillcsr_kernel<<<(EE + 255) / 256, 256, 0, stream>>>(es, ed, offs, cursor, dinv,
                                                         csrc, cnorm, EE);
    agg_kernel<<<NN, 128, 0, stream>>>(xw1, csrc, cnorm, offs, dinv, convb1, 1, h);
    gemm128_kernel<<<512, 128, 0, stream>>>(h, convW2, h2, NN);
    agg_kernel<<<NN, 128, 0, stream>>>(h2, csrc, cnorm, offs, dinv, convb2, 0,
                                       hbufs + (size_t)t * NN * HH);
    mask_kernel<<<(KK * HH + 255) / 256, 256, 0, stream>>>(
        node_t + (size_t)t * KK, hbufs + (size_t)t * NN * HH, KK);
  }

  // One fused launch: items [0, 7*NN) = (t=1..7, node); item 7*NN = (t=0, node 0)
  const int total_items = 7 * NN + 1;
  const int nblocks = 1024;
  const int niter = (total_items + nblocks - 1) / nblocks;
  mixer13_kernel<<<nblocks, 256, 0, stream>>>(hbufs, tn_g, tn_b, tok_w1, tok_b1, tok_w2,
                                              tok_b2, cn_g, cn_b, ch_w1, ch_b1, ch_w2,
                                              ch_b2, out, total_items, niter);
  bcast_kernel<<<((NN * HH - 128) + 255) / 256, 256, 0, stream>>>(out, NN * HH);
}

// Round 14
// 3939.471 us; speedup vs baseline: 1.6058x; 1.3550x over previous
//
#include <hip/hip_runtime.h>
#include <hip/hip_bf16.h>
#include <cstdint>
#include <cstddef>

#define NN 20000
#define HH 128
#define MM 16
#define KK 4000
#define EE 400000

typedef __attribute__((ext_vector_type(16))) float f16v;
typedef __attribute__((ext_vector_type(8))) short short8;   // MFMA A/B operand
typedef __attribute__((ext_vector_type(4))) float f32x4;    // MFMA accumulator
typedef __attribute__((ext_vector_type(4), may_alias)) float f4ma;
typedef __attribute__((ext_vector_type(2), may_alias)) float f2ma;

__device__ __forceinline__ float gelu_f(float x) {
  return 0.5f * x * (1.0f + erff(x * 0.70710678118654752440f));
}

__device__ __forceinline__ short f2bf(float f) {
  union { float f; unsigned u; } v; v.f = f;
  unsigned u = v.u;
  unsigned r = (u + 0x7FFFu + ((u >> 16) & 1u)) >> 16;  // RNE
  return (short)r;
}
__device__ __forceinline__ float bf2f(unsigned short s) {
  union { unsigned u; float f; } v; v.u = ((unsigned)s) << 16; return v.f;
}

// ---------------- GCN helper kernels (validated) ----------------

__global__ void zero2_kernel(int* __restrict__ a, int* __restrict__ b, int n) {
  int i = blockIdx.x * 256 + threadIdx.x;
  if (i < n) { a[i] = 0; b[i] = 0; }
}

__global__ void count_kernel(const int* __restrict__ dst, int* __restrict__ cnt, int n) {
  int e = blockIdx.x * 256 + threadIdx.x;
  if (e < n) atomicAdd(&cnt[dst[e]], 1);
}

__global__ void dinv_kernel(const int* __restrict__ cnt, float* __restrict__ dinv, int n) {
  int i = blockIdx.x * 256 + threadIdx.x;
  if (i < n) dinv[i] = rsqrtf((float)(cnt[i] + 1));
}

__global__ void scan_kernel(const int* __restrict__ cnt, int* __restrict__ offs, int n) {
  __shared__ int sh[1024];
  __shared__ int carry_s;
  int tid = threadIdx.x;
  if (tid == 0) carry_s = 0;
  __syncthreads();
  for (int base = 0; base < n; base += 1024) {
    int i = base + tid;
    int v = (i < n) ? cnt[i] : 0;
    sh[tid] = v;
    __syncthreads();
    for (int off = 1; off < 1024; off <<= 1) {
      int t = (tid >= off) ? sh[tid - off] : 0;
      __syncthreads();
      sh[tid] += t;
      __syncthreads();
    }
    int carry = carry_s;
    if (i < n) offs[i] = carry + sh[tid] - v;
    __syncthreads();
    if (tid == 1023) carry_s = carry + sh[1023];
    __syncthreads();
  }
  if (tid == 0) offs[n] = carry_s;
}

__global__ void fillcsr_kernel(const int* __restrict__ esrc, const int* __restrict__ edst,
                               const int* __restrict__ offs, int* __restrict__ cursor,
                               const float* __restrict__ dinv,
                               int* __restrict__ csrc, float* __restrict__ cnorm, int n) {
  int e = blockIdx.x * 256 + threadIdx.x;
  if (e < n) {
    int s = esrc[e], d = edst[e];
    int pos = offs[d] + atomicAdd(&cursor[d], 1);
    csrc[pos] = s;
    cnorm[pos] = dinv[s] * dinv[d];
  }
}

__global__ __launch_bounds__(128) void agg_kernel(const float* __restrict__ X,
    const int* __restrict__ csrc, const float* __restrict__ cnorm,
    const int* __restrict__ offs, const float* __restrict__ dinv,
    const float* __restrict__ bias, int relu, float* __restrict__ Y) {
  int i = blockIdx.x, c = threadIdx.x;
  float di = dinv[i];
  float acc = X[(size_t)i * HH + c] * di * di;
  int s = offs[i], e = offs[i + 1];
  for (int j = s; j < e; ++j) {
    acc += X[(size_t)csrc[j] * HH + c] * cnorm[j];
  }
  acc += bias[c];
  if (relu) acc = fmaxf(acc, 0.f);
  Y[(size_t)i * HH + c] = acc;
}

__global__ __launch_bounds__(128) void gemm128_kernel(const float* __restrict__ X,
    const float* __restrict__ W, float* __restrict__ Y, int nrows) {
  __shared__ float Ws[128 * 129];
  __shared__ float Xs[8 * 128];
  int tid = threadIdx.x;
  for (int idx = tid; idx < 16384; idx += 128) {
    int o = idx >> 7, k = idx & 127;
    Ws[o * 129 + k] = W[idx];
  }
  __syncthreads();
  for (int row0 = blockIdx.x * 8; row0 < nrows; row0 += gridDim.x * 8) {
    int nr = min(8, nrows - row0);
    for (int idx = tid; idx < nr * 128; idx += 128) Xs[idx] = X[(size_t)row0 * 128 + idx];
    __syncthreads();
    float acc[8] = {0, 0, 0, 0, 0, 0, 0, 0};
    for (int k = 0; k < 128; ++k) {
      float w = Ws[tid * 129 + k];
#pragma unroll
      for (int r = 0; r < 8; ++r) acc[r] += w * Xs[r * 128 + k];
    }
    for (int r = 0; r < nr; ++r) Y[(size_t)(row0 + r) * 128 + tid] = acc[r];
    __syncthreads();
  }
}

__global__ void mask_kernel(const int* __restrict__ nodes, float* __restrict__ H, int kn) {
  int idx = blockIdx.x * 256 + threadIdx.x;
  if (idx < kn * HH) {
    int j = idx >> 7, c = idx & 127;
    H[(size_t)nodes[j] * HH + c] = 0.f;
  }
}

__global__ void bcast_kernel(float* __restrict__ out, int total) {
  int idx = blockIdx.x * 256 + threadIdx.x + 128;
  if (idx < total) out[idx] = out[idx & 127];
}

// ---------------- mixer v14: 4 nodes per block-iteration ----------------
// Block-cooperative skeleton (codegen-clean class), amortized 4x:
// tile zw[64][132] (4 nodes x 16 tokens). P2 uses ALL 256 threads (thread owns
// col c of nodes n0 and n0+2; weight rows read as float4, shared across both).
// MFMA phases: wave wv owns og pair {2wv,2wv+1} across 4 row-tiles (rt = node).
// Math/layout/quantization identical to validated v12/v13 (absmax 9.77e-4).

__global__ __launch_bounds__(256) void mixer14_kernel(
    const float* __restrict__ hbufs,  // [7][NN][HH]
    const float* __restrict__ tn_g, const float* __restrict__ tn_b,
    const float* __restrict__ tok_w1, const float* __restrict__ tok_b1,
    const float* __restrict__ tok_w2, const float* __restrict__ tok_b2,
    const float* __restrict__ cn_g, const float* __restrict__ cn_b,
    const float* __restrict__ ch_w1, const float* __restrict__ ch_b1,
    const float* __restrict__ ch_w2, const float* __restrict__ ch_b2,
    float* __restrict__ out, int total_items, int niter) {
  __shared__ __align__(16) float zw[64 * 132];  // 33.8 KB: 4-node tile
  __shared__ float fout[4 * 128];               // per-node token-phase colsums
  __shared__ float tg[128], tbv[128], cg[128], cbv[128], cb1v[128], cb2v[128];
  __shared__ float tw1s[256], tw2s[256], tb1s[16], tb2s[16];

  const int tid = threadIdx.x;
  const int lane = tid & 63;
  const int wv = tid >> 6;        // wave 0..3 -> og pair {2wv, 2wv+1}
  const int q = lane >> 4;
  const int h = lane & 15;

  if (tid < 128) {
    tg[tid] = tn_g[tid]; tbv[tid] = tn_b[tid];
    cg[tid] = cn_g[tid]; cbv[tid] = cn_b[tid];
    cb1v[tid] = ch_b1[tid]; cb2v[tid] = ch_b2[tid];
  }
  tw1s[tid] = tok_w1[tid];
  tw2s[tid] = tok_w2[tid];
  if (tid < 16) { tb1s[tid] = tok_b1[tid]; tb2s[tid] = tok_b2[tid]; }

  // Wave-constant B-fragments in registers:
  // wf[ks][j] = W[(2wv+j)*16 + h][ks*32 + q*8 .. +7] as bf16.
  short8 wf1[4][2], wf2[4][2];
#pragma unroll
  for (int ks = 0; ks < 4; ++ks) {
#pragma unroll
    for (int j = 0; j < 2; ++j) {
      int o = (2 * wv + j) * 16 + h;
      int k0 = ks * 32 + q * 8;
      const float* s1 = ch_w1 + o * 128 + k0;
      const float* s2 = ch_w2 + o * 128 + k0;
      short8 p1, p2;
#pragma unroll
      for (int e = 0; e < 8; ++e) { p1[e] = f2bf(s1[e]); p2[e] = f2bf(s2[e]); }
      wf1[ks][j] = p1;
      wf2[ks][j] = p2;
    }
  }
  __syncthreads();

  // P1/P3 thread->cell mapping: row lr (0..63), 4 threads/row, 32 ch each.
  const int lr = tid >> 2;
  const int lq = tid & 3;
  // P2 mapping: col c of nodes n0 and n0+2.
  const int c2 = tid & 127;
  const int n0 = tid >> 7;

  for (int it = 0; it < niter; ++it) {
    const int item4 = it * gridDim.x + blockIdx.x;

    // ---- P1: load 4 nodes, LN1 stats per row -> tile (x + mu,rs) ----
    {
      const int n = lr >> 4, tok = lr & 15;
      const int item = item4 * 4 + n;
      const bool act = item < total_items;
      int t = 0, node = 0;
      if (act && item < 7 * NN) { t = item / NN + 1; node = item % NN; }
      int src_t = tok - (MM - t);
      f4ma x[8];
      if (act && src_t >= 0) {
        const float* hp = hbufs + ((size_t)src_t * NN + node) * HH + lq * 32;
#pragma unroll
        for (int j = 0; j < 8; ++j) x[j] = *(const f4ma*)(hp + 4 * j);
      } else {
#pragma unroll
        for (int j = 0; j < 8; ++j) x[j] = (f4ma){0.f, 0.f, 0.f, 0.f};
      }
      float s = 0.f, ss = 0.f;
#pragma unroll
      for (int j = 0; j < 8; ++j) {
        s += x[j].x + x[j].y + x[j].z + x[j].w;
        ss += x[j].x * x[j].x + x[j].y * x[j].y + x[j].z * x[j].z + x[j].w * x[j].w;
      }
      s += __shfl_xor(s, 1); ss += __shfl_xor(ss, 1);
      s += __shfl_xor(s, 2); ss += __shfl_xor(ss, 2);
      float mu = s * (1.f / 128.f);
      float var = fmaxf(ss * (1.f / 128.f) - mu * mu, 0.f);
      float rs = rsqrtf(var + 1e-5f);
#pragma unroll
      for (int j = 0; j < 8; ++j) *(f4ma*)&zw[lr * 132 + lq * 32 + 4 * j] = x[j];
      if (lq == 0) { zw[lr * 132 + 128] = mu; zw[lr * 132 + 129] = rs; }
    }
    __syncthreads();   // (1)

    // ---- P2: token-MLP, all 256 threads, 2 columns each (nodes n0, n0+2) ----
    {
      const int rb0 = n0 * 16 * 132, rb1 = (n0 + 2) * 16 * 132;
      const float tgc = tg[c2], tbc = tbv[c2];
      f16v xv0, xv1, zv0, zv1;
#pragma unroll
      for (int r = 0; r < 16; ++r) {
        float x0 = zw[rb0 + r * 132 + c2];
        float m0 = zw[rb0 + r * 132 + 128], q0 = zw[rb0 + r * 132 + 129];
        float x1 = zw[rb1 + r * 132 + c2];
        float m1 = zw[rb1 + r * 132 + 128], q1 = zw[rb1 + r * 132 + 129];
        xv0[r] = x0; xv1[r] = x1;
        zv0[r] = (x0 - m0) * q0 * tgc + tbc;
        zv1[r] = (x1 - m1) * q1 * tgc + tbc;
      }
      f16v a0v, a1v;
#pragma unroll
      for (int hd = 0; hd < 16; ++hd) {
        float acc0 = tb1s[hd], acc1 = tb1s[hd];
#pragma unroll
        for (int rq = 0; rq < 4; ++rq) {
          f4ma w = *(const f4ma*)&tw1s[hd * 16 + rq * 4];
          acc0 += w.x * zv0[rq * 4] + w.y * zv0[rq * 4 + 1] +
                  w.z * zv0[rq * 4 + 2] + w.w * zv0[rq * 4 + 3];
          acc1 += w.x * zv1[rq * 4] + w.y * zv1[rq * 4 + 1] +
                  w.z * zv1[rq * 4 + 2] + w.w * zv1[rq * 4 + 3];
        }
        a0v[hd] = gelu_f(acc0); a1v[hd] = gelu_f(acc1);
      }
      float cs0 = 0.f, cs1 = 0.f;
#pragma unroll
      for (int r = 0; r < 16; ++r) {
        float o0 = tb2s[r], o1 = tb2s[r];
#pragma unroll
        for (int hq = 0; hq < 4; ++hq) {
          f4ma w = *(const f4ma*)&tw2s[r * 16 + hq * 4];
          o0 += w.x * a0v[hq * 4] + w.y * a0v[hq * 4 + 1] +
                w.z * a0v[hq * 4 + 2] + w.w * a0v[hq * 4 + 3];
          o1 += w.x * a1v[hq * 4] + w.y * a1v[hq * 4 + 1] +
                w.z * a1v[hq * 4 + 2] + w.w * a1v[hq * 4 + 3];
        }
        float nx0 = xv0[r] + o0, nx1 = xv1[r] + o1;
        cs0 += nx0; cs1 += nx1;
        zw[rb0 + r * 132 + c2] = nx0;
        zw[rb1 + r * 132 + c2] = nx1;
      }
      fout[n0 * 128 + c2] = cs0;
      fout[(n0 + 2) * 128 + c2] = cs1;
    }
    __syncthreads();   // (2)

    // ---- P3: LN2 per row, cell-private in-place ----
    {
      f4ma x[8];
#pragma unroll
      for (int j = 0; j < 8; ++j) x[j] = *(const f4ma*)&zw[lr * 132 + lq * 32 + 4 * j];
      float s = 0.f, ss = 0.f;
#pragma unroll
      for (int j = 0; j < 8; ++j) {
        s += x[j].x + x[j].y + x[j].z + x[j].w;
        ss += x[j].x * x[j].x + x[j].y * x[j].y + x[j].z * x[j].z + x[j].w * x[j].w;
      }
      s += __shfl_xor(s, 1); ss += __shfl_xor(ss, 1);
      s += __shfl_xor(s, 2); ss += __shfl_xor(ss, 2);
      float mu = s * (1.f / 128.f);
      float var = fmaxf(ss * (1.f / 128.f) - mu * mu, 0.f);
      float rs = rsqrtf(var + 1e-5f);
#pragma unroll
      for (int j = 0; j < 8; ++j) {
        int c = lq * 32 + 4 * j;
        f4ma z;
        z.x = (x[j].x - mu) * rs * cg[c]     + cbv[c];
        z.y = (x[j].y - mu) * rs * cg[c + 1] + cbv[c + 1];
        z.z = (x[j].z - mu) * rs * cg[c + 2] + cbv[c + 2];
        z.w = (x[j].w - mu) * rs * cg[c + 3] + cbv[c + 3];
        *(f4ma*)&zw[lr * 132 + c] = z;
      }
    }
    __syncthreads();   // (3)

    // ---- P4: MFMA matmul1 over 4 row-tiles -> hidden ----
    {
      f32x4 acc[4][2];
#pragma unroll
      for (int rt = 0; rt < 4; ++rt) {
#pragma unroll
        for (int j = 0; j < 2; ++j) {
          float b = cb1v[(2 * wv + j) * 16 + h];
          acc[rt][j] = (f32x4){b, b, b, b};
        }
      }
#pragma unroll
      for (int ks = 0; ks < 4; ++ks) {
        short8 ah[4], al[4];
#pragma unroll
        for (int rt = 0; rt < 4; ++rt) {
          f4ma v0 = *(const f4ma*)&zw[(rt * 16 + h) * 132 + ks * 32 + q * 8];
          f4ma v1 = *(const f4ma*)&zw[(rt * 16 + h) * 132 + ks * 32 + q * 8 + 4];
          float e[8] = {v0.x, v0.y, v0.z, v0.w, v1.x, v1.y, v1.z, v1.w};
          short8 th, tl;
#pragma unroll
          for (int j = 0; j < 8; ++j) {
            short hi = f2bf(e[j]);
            th[j] = hi;
            tl[j] = f2bf(e[j] - bf2f((unsigned short)hi));
          }
          ah[rt] = th; al[rt] = tl;
        }
#pragma unroll
        for (int rt = 0; rt < 4; ++rt) {
#pragma unroll
          for (int j = 0; j < 2; ++j) {
            acc[rt][j] = __builtin_amdgcn_mfma_f32_16x16x32_bf16(ah[rt], wf1[ks][j], acc[rt][j], 0, 0, 0);
            acc[rt][j] = __builtin_amdgcn_mfma_f32_16x16x32_bf16(al[rt], wf1[ks][j], acc[rt][j], 0, 0, 0);
          }
        }
      }
      __syncthreads();   // (4) all A reads of z2 done before hidden overwrite
#pragma unroll
      for (int rt = 0; rt < 4; ++rt) {
#pragma unroll
        for (int j = 0; j < 2; ++j) {
#pragma unroll
          for (int rg = 0; rg < 4; ++rg) {
            zw[(rt * 16 + q * 4 + rg) * 132 + (2 * wv + j) * 16 + h] = gelu_f(acc[rt][j][rg]);
          }
        }
      }
    }
    __syncthreads();   // (5) hidden visible

    // ---- P5: MFMA matmul2 + per-node colsum + output ----
    {
      f32x4 acc[4][2];
#pragma unroll
      for (int rt = 0; rt < 4; ++rt) {
#pragma unroll
        for (int j = 0; j < 2; ++j) {
          float b = cb2v[(2 * wv + j) * 16 + h];
          acc[rt][j] = (f32x4){b, b, b, b};
        }
      }
#pragma unroll
      for (int ks = 0; ks < 4; ++ks) {
        short8 ah[4], al[4];
#pragma unroll
        for (int rt = 0; rt < 4; ++rt) {
          f4ma v0 = *(const f4ma*)&zw[(rt * 16 + h) * 132 + ks * 32 + q * 8];
          f4ma v1 = *(const f4ma*)&zw[(rt * 16 + h) * 132 + ks * 32 + q * 8 + 4];
          float e[8] = {v0.x, v0.y, v0.z, v0.w, v1.x, v1.y, v1.z, v1.w};
          short8 th, tl;
#pragma unroll
          for (int j = 0; j < 8; ++j) {
            short hi = f2bf(e[j]);
            th[j] = hi;
            tl[j] = f2bf(e[j] - bf2f((unsigned short)hi));
          }
          ah[rt] = th; al[rt] = tl;
        }
#pragma unroll
        for (int rt = 0; rt < 4; ++rt) {
#pragma unroll
          for (int j = 0; j < 2; ++j) {
            acc[rt][j] = __builtin_amdgcn_mfma_f32_16x16x32_bf16(ah[rt], wf2[ks][j], acc[rt][j], 0, 0, 0);
            acc[rt][j] = __builtin_amdgcn_mfma_f32_16x16x32_bf16(al[rt], wf2[ks][j], acc[rt][j], 0, 0, 0);
          }
        }
      }
#pragma unroll
      for (int rt = 0; rt < 4; ++rt) {
        const int item = item4 * 4 + rt;
        const bool act = item < total_items;
        int t = 0, node = 0;
        if (act && item < 7 * NN) { t = item / NN + 1; node = item % NN; }
#pragma unroll
        for (int j = 0; j < 2; ++j) {
          float v = acc[rt][j][0] + acc[rt][j][1] + acc[rt][j][2] + acc[rt][j][3];
          v += __shfl_xor(v, 16);
          v += __shfl_xor(v, 32);
          if (q == 0 && act) {
            int col = (2 * wv + j) * 16 + h;
            out[((size_t)t * NN + node) * HH + col] = (fout[rt * 128 + col] + v) * (1.f / 16.f);
          }
        }
      }
    }
    __syncthreads();   // (6) tile + fout reuse next iteration
  }
}

// ---------------- launch ----------------

extern "C" void kernel_launch(void* const* d_in, const int* in_sizes, int n_in,
                              void* d_out, int out_size, void* d_ws, size_t ws_size,
                              hipStream_t stream) {
  const int* node_t   = (const int*)d_in[0];
  const int* edges    = (const int*)d_in[1];
  const float* emb    = (const float*)d_in[3];
  const float* convW1 = (const float*)d_in[4];
  const float* convb1 = (const float*)d_in[5];
  const float* convW2 = (const float*)d_in[6];
  const float* convb2 = (const float*)d_in[7];
  const float* tn_g   = (const float*)d_in[8];
  const float* tn_b   = (const float*)d_in[9];
  const float* tok_w1 = (const float*)d_in[10];
  const float* tok_b1 = (const float*)d_in[11];
  const float* tok_w2 = (const float*)d_in[12];
  const float* tok_b2 = (const float*)d_in[13];
  const float* cn_g   = (const float*)d_in[14];
  const float* cn_b   = (const float*)d_in[15];
  const float* ch_w1  = (const float*)d_in[16];
  const float* ch_b1  = (const float*)d_in[17];
  const float* ch_w2  = (const float*)d_in[18];
  const float* ch_b2  = (const float*)d_in[19];
  float* out = (float*)d_out;

  char* ws = (char*)d_ws;
  size_t off = 0;
  auto alloc = [&](size_t bytes) -> void* {
    void* p = ws + off;
    off += (bytes + 511) & ~(size_t)511;
    return p;
  };
  float* xw1   = (float*)alloc((size_t)NN * HH * 4);
  float* hbufs = (float*)alloc((size_t)7 * NN * HH * 4);
  float* h     = (float*)alloc((size_t)NN * HH * 4);
  float* h2    = (float*)alloc((size_t)NN * HH * 4);
  float* dinv  = (float*)alloc((size_t)NN * 4);
  int*   cnt   = (int*)alloc((size_t)NN * 4);
  int*   cursor= (int*)alloc((size_t)NN * 4);
  int*   offs  = (int*)alloc((size_t)(NN + 1) * 4);
  int*   csrc  = (int*)alloc((size_t)EE * 4);
  float* cnorm = (float*)alloc((size_t)EE * 4);

  gemm128_kernel<<<512, 128, 0, stream>>>(emb, convW1, xw1, NN);

  for (int t = 0; t < 7; ++t) {
    const int* es = edges + (size_t)t * 2 * EE;
    const int* ed = es + EE;
    zero2_kernel<<<(NN + 255) / 256, 256, 0, stream>>>(cnt, cursor, NN);
    count_kernel<<<(EE + 255) / 256, 256, 0, stream>>>(ed, cnt, EE);
    dinv_kernel<<<(NN + 255) / 256, 256, 0, stream>>>(cnt, dinv, NN);
    scan_kernel<<<1, 1024, 0, stream>>>(cnt, offs, NN);
    fillcsr_kernel<<<(EE + 255) / 256, 256, 0, stream>>>(es, ed, offs, cursor, dinv,
                                                         csrc, cnorm, EE);
    agg_kernel<<<NN, 128, 0, stream>>>(xw1, csrc, cnorm, offs, dinv, convb1, 1, h);
    gemm128_kernel<<<512, 128, 0, stream>>>(h, convW2, h2, NN);
    agg_kernel<<<NN, 128, 0, stream>>>(h2, csrc, cnorm, offs, dinv, convb2, 0,
                                       hbufs + (size_t)t * NN * HH);
    mask_kernel<<<(KK * HH + 255) / 256, 256, 0, stream>>>(
        node_t + (size_t)t * KK, hbufs + (size_t)t * NN * HH, KK);
  }

  // Fused mixer: items [0, 7*NN) = (t=1..7, node); item 7*NN = (t=0, node 0)
  const int total_items = 7 * NN + 1;
  const int nblocks = 2048;
  const int item4s = (total_items + 3) / 4;
  const int niter = (item4s + nblocks - 1) / nblocks;
  mixer14_kernel<<<nblocks, 256, 0, stream>>>(hbufs, tn_g, tn_b, tok_w1, tok_b1, tok_w2,
                                              tok_b2, cn_g, cn_b, ch_w1, ch_b1, ch_w2,
                                              ch_b2, out, total_items, niter);
  bcast_kernel<<<((NN * HH - 128) + 255) / 256, 256, 0, stream>>>(out, NN * HH);
}